// Round 21
// baseline (1305.758 us; speedup 1.0000x reference)
//
#include <hip/hip_runtime.h>
#include <hip/hip_bf16.h>

#define NFEAT 256
#define HID 64
#define NCLASS 40
#define NUM_LAYERS 3

typedef unsigned short u16;
typedef unsigned int   u32;
typedef float    f32x4  __attribute__((ext_vector_type(4)));
typedef short    s16x8  __attribute__((ext_vector_type(8)));
typedef short    s16x16 __attribute__((ext_vector_type(16)));
typedef u32      u32x8  __attribute__((ext_vector_type(8)));
typedef _Float16 h16x8  __attribute__((ext_vector_type(8)));

// fp16 hi/lo split: hi = (f16)f, lo = (f16)(f - hi) -> ~22-23 mantissa bits
__device__ __forceinline__ u16 f2h(float f) {
    _Float16 h = (_Float16)f;
    return __builtin_bit_cast(u16, h);
}
__device__ __forceinline__ float h2f(u16 s) {
    return (float)__builtin_bit_cast(_Float16, s);
}
__device__ __forceinline__ u32 packhl(float f) {
    u16 hi = f2h(f);
    u16 lo = f2h(f - h2f(hi));
    return (u32)hi | ((u32)lo << 16);
}
__device__ __forceinline__ float unpackhl(u32 v) {
    return h2f((u16)v) + h2f((u16)(v >> 16));
}

// BUILTIN MFMA (r18/r19 lesson: raw inline-asm MFMA is opaque to the hazard
// recognizer; the builtin gets compiler-inserted wait states. r19-verified.)
__device__ __forceinline__ f32x4 mfma_f16(s16x8 a, s16x8 b, f32x4 c) {
    return __builtin_amdgcn_mfma_f32_16x16x32_f16(
        __builtin_bit_cast(h16x8, a), __builtin_bit_cast(h16x8, b), c, 0, 0, 0);
}

// ---------------------------------------------------------------------------
// lin1: h = relu(x @ w1.T + b1) -> packed f16 hi|lo u32 into H0[n][64]
// ---------------------------------------------------------------------------
__global__ __launch_bounds__(256) void k_lin1(
    const float* __restrict__ x, const float* __restrict__ w1,
    const float* __restrict__ b1, u32* __restrict__ H0, int n_nodes)
{
    __shared__ float xs[8][NFEAT];
    __shared__ float part[4][8][HID];
    const int tid  = threadIdx.x;
    const int wave = tid >> 6;
    const int lane = tid & 63;

    float wreg[64];
#pragma unroll
    for (int k = 0; k < 64; k += 4) {
        float4 v = *reinterpret_cast<const float4*>(&w1[lane * NFEAT + wave * 64 + k]);
        wreg[k] = v.x; wreg[k + 1] = v.y; wreg[k + 2] = v.z; wreg[k + 3] = v.w;
    }

    const int nbatch = (n_nodes + 7) >> 3;
    for (int batch = blockIdx.x; batch < nbatch; batch += gridDim.x) {
        const int n0 = batch * 8;
        {
            const float4* xg = reinterpret_cast<const float4*>(x + (size_t)n0 * NFEAT);
            float4* xsv = reinterpret_cast<float4*>(&xs[0][0]);
#pragma unroll
            for (int i = 0; i < 2; ++i) {
                int idx  = tid + i * 256;
                int node = n0 + (idx >> 6);
                xsv[idx] = (node < n_nodes) ? xg[idx] : make_float4(0.f, 0.f, 0.f, 0.f);
            }
        }
        __syncthreads();
        for (int nl = 0; nl < 8; ++nl) {
            const float4* xrow = reinterpret_cast<const float4*>(&xs[nl][wave * 64]);
            float a0 = 0.f, a1 = 0.f, a2 = 0.f, a3 = 0.f;
#pragma unroll
            for (int kq = 0; kq < 16; ++kq) {
                float4 v = xrow[kq];
                a0 = fmaf(v.x, wreg[4 * kq + 0], a0);
                a1 = fmaf(v.y, wreg[4 * kq + 1], a1);
                a2 = fmaf(v.z, wreg[4 * kq + 2], a2);
                a3 = fmaf(v.w, wreg[4 * kq + 3], a3);
            }
            part[wave][nl][lane] = (a0 + a1) + (a2 + a3);
        }
        __syncthreads();
#pragma unroll
        for (int i = 0; i < 2; ++i) {
            int o = tid + i * 256;
            int nl = o >> 6, j = o & 63;
            int node = n0 + nl;
            if (node < n_nodes) {
                float v = part[0][nl][j] + part[1][nl][j] + part[2][nl][j] + part[3][nl][j]
                          + b1[j];
                H0[(size_t)node * 64 + j] = packhl(fmaxf(v, 0.f));
            }
        }
        __syncthreads();
    }
}

// ---------------------------------------------------------------------------
// CSR build (int32 edge_index)
// ---------------------------------------------------------------------------
__global__ void k_hist(const int* __restrict__ ei, int* __restrict__ cnt, int E)
{
    int i = blockIdx.x * blockDim.x + threadIdx.x;
    if (i < E) atomicAdd(&cnt[ei[E + i]], 1);
}

#define SCAN_C 2048
__global__ __launch_bounds__(512) void k_scan1(const int* __restrict__ cnt,
                                               int* __restrict__ btot, int n)
{
    __shared__ int sd[512];
    int b = blockIdx.x, t = threadIdx.x;
    int base = b * SCAN_C + t * 4;
    int s = 0;
#pragma unroll
    for (int i = 0; i < 4; ++i) { int idx = base + i; if (idx < n) s += cnt[idx]; }
    sd[t] = s; __syncthreads();
    for (int off = 256; off > 0; off >>= 1) {
        if (t < off) sd[t] += sd[t + off];
        __syncthreads();
    }
    if (t == 0) btot[b] = sd[0];
}

__global__ __launch_bounds__(1024) void k_scan2(int* __restrict__ btot, int nb)
{
    __shared__ int sd[1024];
    int t = threadIdx.x;
    int v = (t < nb) ? btot[t] : 0;
    sd[t] = v; __syncthreads();
    for (int off = 1; off < 1024; off <<= 1) {
        int x = sd[t];
        int add = (t >= off) ? sd[t - off] : 0;
        __syncthreads();
        sd[t] = x + add;
        __syncthreads();
    }
    if (t < nb) btot[t] = sd[t] - v;  // exclusive
}

__global__ __launch_bounds__(512) void k_scan3(const int* __restrict__ cnt,
                                               const int* __restrict__ btot,
                                               int* __restrict__ row_ptr,
                                               int* __restrict__ cursor, int n)
{
    __shared__ int sth[512];
    int b = blockIdx.x, t = threadIdx.x;
    int base = b * SCAN_C + t * 4;
    int v[4]; int s = 0;
#pragma unroll
    for (int i = 0; i < 4; ++i) { int idx = base + i; v[i] = (idx < n) ? cnt[idx] : 0; s += v[i]; }
    sth[t] = s; __syncthreads();
    int mine = s;
    for (int off = 1; off < 512; off <<= 1) {
        int x = sth[t];
        int add = (t >= off) ? sth[t - off] : 0;
        __syncthreads();
        sth[t] = x + add;
        __syncthreads();
    }
    int carry = btot[b] + (sth[t] - mine);
#pragma unroll
    for (int i = 0; i < 4; ++i) {
        int idx = base + i;
        if (idx < n) {
            row_ptr[idx] = carry;
            cursor[idx]  = carry;
            carry += v[i];
            if (idx == n - 1) row_ptr[n] = carry;  // = E
        }
    }
}

__global__ void k_fill(const int* __restrict__ ei, int* __restrict__ cursor,
                       int* __restrict__ col_src, int E)
{
    int i = blockIdx.x * blockDim.x + threadIdx.x;
    if (i < E) {
        int dst = ei[E + i];
        int p = atomicAdd(&cursor[dst], 1);
        col_src[p] = ei[i];
    }
}

// ---------------------------------------------------------------------------
// Wic[l][j][k] = sum_m w_ih[j][m] * gg_w[l][k][m]  (fp32 staging)
// ---------------------------------------------------------------------------
__global__ void k_wic(const float* __restrict__ gg_w, const float* __restrict__ w_ih,
                      float* __restrict__ Wic)
{
    int idx = blockIdx.x * blockDim.x + threadIdx.x;
    if (idx < NUM_LAYERS * 192 * 64) {
        int l = idx / (192 * 64);
        int j = (idx / 64) % 192;
        int k = idx % 64;
        const float* gw = gg_w + ((size_t)l * 64 + k) * 64;
        const float* wi = w_ih + (size_t)j * 64;
        float acc = 0.f;
#pragma unroll 4
        for (int m = 0; m < 64; ++m) acc = fmaf(wi[m], gw[m], acc);
        Wic[idx] = acc;
    }
}

// ---------------------------------------------------------------------------
// W' pack: [3][256][128] f16 hi/lo, SPLIT arrays. Rows 0-63: r; 64-127: z
// (both [Wic | whh]); 128-191: [Wic_n | 0]; 192-255: [0 | whh_n].
// ---------------------------------------------------------------------------
__global__ void k_wpack(const float* __restrict__ Wic, const float* __restrict__ whh,
                        u16* __restrict__ Wphi, u16* __restrict__ Wplo)
{
    int idx = blockIdx.x * 256 + threadIdx.x;
    if (idx >= NUM_LAYERS * 256 * 128) return;
    int l = idx / (256 * 128);
    int n = (idx / 128) & 255;
    int k = idx & 127;
    float v;
    if (n < 128)      v = (k < 64) ? Wic[((size_t)l * 192 + n) * 64 + k] : whh[(size_t)n * 64 + (k - 64)];
    else if (n < 192) v = (k < 64) ? Wic[((size_t)l * 192 + n) * 64 + k] : 0.f;
    else              v = (k < 64) ? 0.f : whh[(size_t)(n - 64) * 64 + (k - 64)];
    u16 hi = f2h(v);
    Wphi[idx] = hi;
    Wplo[idx] = f2h(v - h2f(hi));
}

// ---------------------------------------------------------------------------
// FUSED gather + GRU (k_gruF): block = 64 nodes, 4 waves x 16 nodes.
// Ping-pong h (Hold -> Hnew, both [n][64] packed u32): removes the in-place
// hazard AND makes fusion race-free (gather reads only Hold; Hnew written
// only for own rows). Phase 1 (per wave, no barrier — own rows only): gather
// ah for its 16 nodes into LDS xa[64][65] (pad -> 2-way banks = free, m136).
// Phase 2: r19-VERIFIED gru8 MFMA core; A-frags s=0,1 from LDS ah (8x
// ds_read_b32, conflict-free), s=2,3 from global Hold (uint4+shuffle, r19
// path). Epilogue hold from Hold, write Hnew. Gather latency now overlaps
// other waves' MFMA instead of occupying a separate serialized kernel.
// ---------------------------------------------------------------------------
__global__ __launch_bounds__(256) void k_gruF(
    const u32* __restrict__ Hold, u32* __restrict__ Hnew,
    const int* __restrict__ row_ptr, const int* __restrict__ col_src,
    const u16* __restrict__ Wphi, const u16* __restrict__ Wplo,
    const float* __restrict__ b_ih, const float* __restrict__ b_hh,
    int n_nodes)
{
    __shared__ u32 xa[64][65];  // ah tile, 16.6 KB

    const int l    = threadIdx.x & 63;
    const int wv   = threadIdx.x >> 6;
    const int base = blockIdx.x * 64 + wv * 16;  // this wave's 16-node tile

    // ---- phase 1: gather ah for own 16 nodes (lane = feature) ----
#pragma unroll 1
    for (int i = 0; i < 16; ++i) {
        const int lm   = wv * 16 + i;
        const int node = blockIdx.x * 64 + lm;
        float acc = 0.f;
        if (node < n_nodes) {
            int e0 = row_ptr[node], e1 = row_ptr[node + 1];
            int e = e0;
            for (; e + 4 <= e1; e += 4) {
                int s0 = col_src[e], s1 = col_src[e + 1];
                int s2 = col_src[e + 2], s3 = col_src[e + 3];
                float v0 = unpackhl(Hold[(size_t)s0 * 64 + l]);
                float v1 = unpackhl(Hold[(size_t)s1 * 64 + l]);
                float v2 = unpackhl(Hold[(size_t)s2 * 64 + l]);
                float v3 = unpackhl(Hold[(size_t)s3 * 64 + l]);
                acc += (v0 + v1) + (v2 + v3);
            }
            for (; e < e1; ++e)
                acc += unpackhl(Hold[(size_t)col_src[e] * 64 + l]);
        }
        xa[lm][l] = packhl(acc);
    }
    // no __syncthreads: each wave reads only the LDS rows it wrote

    if (base >= n_nodes) return;

    // ---- phase 2: MFMA (r19 gru8 core) ----
    const int lrow = l & 15;
    const int lk   = (l >> 4) * 8;

    int arow = base + lrow;
    if (arow > n_nodes - 1) arow = n_nodes - 1;

    f32x4 acc[16];
#pragma unroll
    for (int t = 0; t < 16; ++t) acc[t] = f32x4{0.f, 0.f, 0.f, 0.f};

#pragma unroll
    for (int s = 0; s < 4; ++s) {
        s16x8 ahi, alo;
        if (s < 2) {
            // ah from LDS (own-wave rows; cols s*32+lk .. +7)
            u32x8 w;
#pragma unroll
            for (int i = 0; i < 8; ++i) w[i] = xa[wv * 16 + lrow][s * 32 + lk + i];
            s16x16 p = __builtin_bit_cast(s16x16, w);
            ahi = __builtin_shufflevector(p, p, 0, 2, 4, 6, 8, 10, 12, 14);
            alo = __builtin_shufflevector(p, p, 1, 3, 5, 7, 9, 11, 13, 15);
        } else {
            // h from global Hold (cols (s-2)*32+lk .. +7 of the h half)
            const uint4* pa = reinterpret_cast<const uint4*>(
                Hold + (size_t)arow * 64 + (s - 2) * 32 + lk);
            uint4 w0 = pa[0], w1 = pa[1];
            s16x8 p0 = __builtin_bit_cast(s16x8, w0);
            s16x8 p1 = __builtin_bit_cast(s16x8, w1);
            ahi = __builtin_shufflevector(p0, p1, 0, 2, 4, 6, 8, 10, 12, 14);
            alo = __builtin_shufflevector(p0, p1, 1, 3, 5, 7, 9, 11, 13, 15);
        }
#pragma unroll
        for (int t = 0; t < 16; ++t) {
            const bool valid = (t < 8) || (t < 12 ? (s < 2) : (s >= 2));
            if (!valid) continue;  // compile-time after unroll
            const size_t woff = (size_t)(t * 16 + lrow) * 128 + s * 32 + lk;
            s16x8 bhi = *reinterpret_cast<const s16x8*>(Wphi + woff);
            s16x8 blo = *reinterpret_cast<const s16x8*>(Wplo + woff);
            acc[t] = mfma_f16(ahi, bhi, acc[t]);
            acc[t] = mfma_f16(alo, bhi, acc[t]);
            acc[t] = mfma_f16(ahi, blo, acc[t]);
            acc[t] = mfma_f16(alo, blo, acc[t]);
        }
    }

    const int quarter = l >> 4;
    const int c = lrow;
#pragma unroll
    for (int r = 0; r < 4; ++r) {
        int m = base + quarter * 4 + r;
        if (m < n_nodes) {
#pragma unroll
            for (int q = 0; q < 4; ++q) {
                int j = q * 16 + c;
                float rv = acc[q][r]      + b_ih[j]       + b_hh[j];
                float zv = acc[4 + q][r]  + b_ih[64 + j]  + b_hh[64 + j];
                float iv = acc[8 + q][r]  + b_ih[128 + j];
                float hv = acc[12 + q][r] + b_hh[128 + j];
                rv = 1.f / (1.f + __expf(-rv));
                zv = 1.f / (1.f + __expf(-zv));
                float x2 = iv + rv * hv;
                float nn = 1.f - 2.f / (__expf(2.f * x2) + 1.f);  // tanh, inf-safe
                float hold = unpackhl(Hold[(size_t)m * 64 + j]);
                Hnew[(size_t)m * 64 + j] = packhl((1.f - zv) * nn + zv * hold);
            }
        }
    }
}

// ---------------------------------------------------------------------------
// out = softmax(h @ w2.T + b2); h read from packed H[n][64]
// ---------------------------------------------------------------------------
__global__ __launch_bounds__(256) void k_out(
    const u32* __restrict__ H, const float* __restrict__ w2,
    const float* __restrict__ b2, float* __restrict__ out, int n_nodes)
{
    const int tid = threadIdx.x, lane = tid & 63;
    float wreg[64];
    float bias = 0.f;
    if (lane < NCLASS) {
#pragma unroll
        for (int k = 0; k < 64; k += 4) {
            float4 v = *reinterpret_cast<const float4*>(&w2[lane * HID + k]);
            wreg[k] = v.x; wreg[k + 1] = v.y; wreg[k + 2] = v.z; wreg[k + 3] = v.w;
        }
        bias = b2[lane];
    } else {
#pragma unroll
        for (int k = 0; k < 64; ++k) wreg[k] = 0.f;
    }
    int wid    = (blockIdx.x * blockDim.x + tid) >> 6;
    int nwaves = (gridDim.x * blockDim.x) >> 6;
    for (int node = wid; node < n_nodes; node += nwaves) {
        const uint4* p4 = reinterpret_cast<const uint4*>(H + (size_t)node * 64);
        float a0 = bias, a1 = 0.f, a2 = 0.f, a3 = 0.f;
#pragma unroll
        for (int kq = 0; kq < 16; ++kq) {
            uint4 v = p4[kq];
            a0 = fmaf(unpackhl(v.x), wreg[4 * kq + 0], a0);
            a1 = fmaf(unpackhl(v.y), wreg[4 * kq + 1], a1);
            a2 = fmaf(unpackhl(v.z), wreg[4 * kq + 2], a2);
            a3 = fmaf(unpackhl(v.w), wreg[4 * kq + 3], a3);
        }
        float lg = (lane < NCLASS) ? (a0 + a1) + (a2 + a3) : -INFINITY;
        float m = lg;
#pragma unroll
        for (int off = 32; off > 0; off >>= 1) m = fmaxf(m, __shfl_xor(m, off, 64));
        float p = (lane < NCLASS) ? __expf(lg - m) : 0.f;
        float s = p;
#pragma unroll
        for (int off = 32; off > 0; off >>= 1) s += __shfl_xor(s, off, 64);
        if (lane < NCLASS) out[(size_t)node * NCLASS + lane] = p / s;
    }
}

// ---------------------------------------------------------------------------
extern "C" void kernel_launch(void* const* d_in, const int* in_sizes, int n_in,
                              void* d_out, int out_size, void* d_ws, size_t ws_size,
                              hipStream_t stream)
{
    const float* x    = (const float*)d_in[0];
    const int*   ei   = (const int*)d_in[1];    // int32 per harness contract
    const float* w1   = (const float*)d_in[2];
    const float* b1   = (const float*)d_in[3];
    const float* gg_w = (const float*)d_in[4];
    const float* w_ih = (const float*)d_in[5];
    const float* w_hh = (const float*)d_in[6];
    const float* b_ih = (const float*)d_in[7];
    const float* b_hh = (const float*)d_in[8];
    const float* w2   = (const float*)d_in[9];
    const float* b2   = (const float*)d_in[10];
    float*       out  = (float*)d_out;

    const int n = in_sizes[0] / NFEAT;   // 200000
    const int E = in_sizes[1] / 2;       // 1200000

    // workspace carve (~111 MB, proven envelope), 256-B aligned slots
    char* ws0 = (char*)d_ws;
    char* ws  = ws0;
    auto carve = [&](size_t bytes) {
        char* p = ws;
        ws += (bytes + 255) & ~(size_t)255;
        return p;
    };
    u32*   H0      = (u32*)carve((size_t)n * 64 * 4);                // 51.2 MB
    u32*   H1      = (u32*)carve((size_t)n * 64 * 4);                // 51.2 MB
    float* Wic     = (float*)carve((size_t)NUM_LAYERS * 192 * 64 * 4);
    u16*   Wphi    = (u16*)carve((size_t)NUM_LAYERS * 256 * 128 * 2);
    u16*   Wplo    = (u16*)carve((size_t)NUM_LAYERS * 256 * 128 * 2);
    int*   row_ptr = (int*)carve((size_t)(n + 1) * 4);
    int*   col_src = (int*)carve((size_t)E * 4);
    int*   cnt     = (int*)carve((size_t)n * 4);
    int*   cursor  = (int*)carve((size_t)n * 4);
    int*   btot    = (int*)carve(8192);

    const int nb = (n + SCAN_C - 1) / SCAN_C;

    hipMemsetAsync(cnt, 0, (size_t)n * 4, stream);
    k_wic<<<(NUM_LAYERS * 192 * 64 + 255) / 256, 256, 0, stream>>>(gg_w, w_ih, Wic);
    k_wpack<<<(NUM_LAYERS * 256 * 128 + 255) / 256, 256, 0, stream>>>(Wic, w_hh, Wphi, Wplo);
    k_lin1<<<2048, 256, 0, stream>>>(x, w1, b1, H0, n);
    k_hist<<<(E + 255) / 256, 256, 0, stream>>>(ei, cnt, E);
    k_scan1<<<nb, 512, 0, stream>>>(cnt, btot, n);
    k_scan2<<<1, 1024, 0, stream>>>(btot, nb);
    k_scan3<<<nb, 512, 0, stream>>>(cnt, btot, row_ptr, cursor, n);
    k_fill<<<(E + 255) / 256, 256, 0, stream>>>(ei, cursor, col_src, E);

    u32* hb[2] = {H0, H1};
    const int gblocks = (n + 63) / 64;  // 3125
    for (int l = 0; l < NUM_LAYERS; ++l) {
        k_gruF<<<gblocks, 256, 0, stream>>>(hb[l & 1], hb[(l + 1) & 1],
                                            row_ptr, col_src,
                                            Wphi + (size_t)l * 256 * 128,
                                            Wplo + (size_t)l * 256 * 128,
                                            b_ih, b_hh, n);
    }
    k_out<<<2048, 256, 0, stream>>>(hb[NUM_LAYERS & 1], w2, b2, out, n);
}

// Round 22
// 1122.031 us; speedup vs baseline: 1.1637x; 1.1637x over previous
//
#include <hip/hip_runtime.h>
#include <hip/hip_bf16.h>

#define NFEAT 256
#define HID 64
#define NCLASS 40
#define NUM_LAYERS 3

typedef unsigned short u16;
typedef unsigned int   u32;
typedef float    f32x4 __attribute__((ext_vector_type(4)));
typedef short    s16x8 __attribute__((ext_vector_type(8)));
typedef _Float16 h16x8 __attribute__((ext_vector_type(8)));

// fp16 hi/lo split: hi = (f16)f, lo = (f16)(f - hi) -> ~22-23 mantissa bits
__device__ __forceinline__ u16 f2h(float f) {
    _Float16 h = (_Float16)f;
    return __builtin_bit_cast(u16, h);
}
__device__ __forceinline__ float h2f(u16 s) {
    return (float)__builtin_bit_cast(_Float16, s);
}
__device__ __forceinline__ u32 packhl(float f) {
    u16 hi = f2h(f);
    u16 lo = f2h(f - h2f(hi));
    return (u32)hi | ((u32)lo << 16);
}
__device__ __forceinline__ float unpackhl(u32 v) {
    return h2f((u16)v) + h2f((u16)(v >> 16));
}

// BUILTIN MFMA (r18/r19 lesson: raw inline-asm MFMA is opaque to the hazard
// recognizer; the builtin gets compiler-inserted wait states. r19-verified.)
__device__ __forceinline__ f32x4 mfma_f16(s16x8 a, s16x8 b, f32x4 c) {
    return __builtin_amdgcn_mfma_f32_16x16x32_f16(
        __builtin_bit_cast(h16x8, a), __builtin_bit_cast(h16x8, b), c, 0, 0, 0);
}

// ---------------------------------------------------------------------------
// lin1: h = relu(x @ w1.T + b1) -> packed f16 hi|lo u32 into Xpk[:,64:128]
// ---------------------------------------------------------------------------
__global__ __launch_bounds__(256) void k_lin1(
    const float* __restrict__ x, const float* __restrict__ w1,
    const float* __restrict__ b1, u32* Xpk, int n_nodes)
{
    __shared__ float xs[8][NFEAT];
    __shared__ float part[4][8][HID];
    const int tid  = threadIdx.x;
    const int wave = tid >> 6;
    const int lane = tid & 63;

    float wreg[64];
#pragma unroll
    for (int k = 0; k < 64; k += 4) {
        float4 v = *reinterpret_cast<const float4*>(&w1[lane * NFEAT + wave * 64 + k]);
        wreg[k] = v.x; wreg[k + 1] = v.y; wreg[k + 2] = v.z; wreg[k + 3] = v.w;
    }

    const int nbatch = (n_nodes + 7) >> 3;
    for (int batch = blockIdx.x; batch < nbatch; batch += gridDim.x) {
        const int n0 = batch * 8;
        {
            const float4* xg = reinterpret_cast<const float4*>(x + (size_t)n0 * NFEAT);
            float4* xsv = reinterpret_cast<float4*>(&xs[0][0]);
#pragma unroll
            for (int i = 0; i < 2; ++i) {
                int idx  = tid + i * 256;
                int node = n0 + (idx >> 6);
                xsv[idx] = (node < n_nodes) ? xg[idx] : make_float4(0.f, 0.f, 0.f, 0.f);
            }
        }
        __syncthreads();
        for (int nl = 0; nl < 8; ++nl) {
            const float4* xrow = reinterpret_cast<const float4*>(&xs[nl][wave * 64]);
            float a0 = 0.f, a1 = 0.f, a2 = 0.f, a3 = 0.f;
#pragma unroll
            for (int kq = 0; kq < 16; ++kq) {
                float4 v = xrow[kq];
                a0 = fmaf(v.x, wreg[4 * kq + 0], a0);
                a1 = fmaf(v.y, wreg[4 * kq + 1], a1);
                a2 = fmaf(v.z, wreg[4 * kq + 2], a2);
                a3 = fmaf(v.w, wreg[4 * kq + 3], a3);
            }
            part[wave][nl][lane] = (a0 + a1) + (a2 + a3);
        }
        __syncthreads();
#pragma unroll
        for (int i = 0; i < 2; ++i) {
            int o = tid + i * 256;
            int nl = o >> 6, j = o & 63;
            int node = n0 + nl;
            if (node < n_nodes) {
                float v = part[0][nl][j] + part[1][nl][j] + part[2][nl][j] + part[3][nl][j]
                          + b1[j];
                Xpk[(size_t)node * 128 + 64 + j] = packhl(fmaxf(v, 0.f));
            }
        }
        __syncthreads();
    }
}

// ---------------------------------------------------------------------------
// CSR build (int32 edge_index)
// ---------------------------------------------------------------------------
__global__ void k_hist(const int* __restrict__ ei, int* __restrict__ cnt, int E)
{
    int i = blockIdx.x * blockDim.x + threadIdx.x;
    if (i < E) atomicAdd(&cnt[ei[E + i]], 1);
}

#define SCAN_C 2048
__global__ __launch_bounds__(512) void k_scan1(const int* __restrict__ cnt,
                                               int* __restrict__ btot, int n)
{
    __shared__ int sd[512];
    int b = blockIdx.x, t = threadIdx.x;
    int base = b * SCAN_C + t * 4;
    int s = 0;
#pragma unroll
    for (int i = 0; i < 4; ++i) { int idx = base + i; if (idx < n) s += cnt[idx]; }
    sd[t] = s; __syncthreads();
    for (int off = 256; off > 0; off >>= 1) {
        if (t < off) sd[t] += sd[t + off];
        __syncthreads();
    }
    if (t == 0) btot[b] = sd[0];
}

__global__ __launch_bounds__(1024) void k_scan2(int* __restrict__ btot, int nb)
{
    __shared__ int sd[1024];
    int t = threadIdx.x;
    int v = (t < nb) ? btot[t] : 0;
    sd[t] = v; __syncthreads();
    for (int off = 1; off < 1024; off <<= 1) {
        int x = sd[t];
        int add = (t >= off) ? sd[t - off] : 0;
        __syncthreads();
        sd[t] = x + add;
        __syncthreads();
    }
    if (t < nb) btot[t] = sd[t] - v;  // exclusive
}

__global__ __launch_bounds__(512) void k_scan3(const int* __restrict__ cnt,
                                               const int* __restrict__ btot,
                                               int* __restrict__ row_ptr,
                                               int* __restrict__ cursor, int n)
{
    __shared__ int sth[512];
    int b = blockIdx.x, t = threadIdx.x;
    int base = b * SCAN_C + t * 4;
    int v[4]; int s = 0;
#pragma unroll
    for (int i = 0; i < 4; ++i) { int idx = base + i; v[i] = (idx < n) ? cnt[idx] : 0; s += v[i]; }
    sth[t] = s; __syncthreads();
    int mine = s;
    for (int off = 1; off < 512; off <<= 1) {
        int x = sth[t];
        int add = (t >= off) ? sth[t - off] : 0;
        __syncthreads();
        sth[t] = x + add;
        __syncthreads();
    }
    int carry = btot[b] + (sth[t] - mine);
#pragma unroll
    for (int i = 0; i < 4; ++i) {
        int idx = base + i;
        if (idx < n) {
            row_ptr[idx] = carry;
            cursor[idx]  = carry;
            carry += v[i];
            if (idx == n - 1) row_ptr[n] = carry;  // = E
        }
    }
}

__global__ void k_fill(const int* __restrict__ ei, int* __restrict__ cursor,
                       int* __restrict__ col_src, int E)
{
    int i = blockIdx.x * blockDim.x + threadIdx.x;
    if (i < E) {
        int dst = ei[E + i];
        int p = atomicAdd(&cursor[dst], 1);
        col_src[p] = ei[i];
    }
}

// ---------------------------------------------------------------------------
// aggregation v4: 2-node interleave for memory-level parallelism. Each wave
// processes nodes (base) and (base+nwaves) concurrently; edge-range branches
// are WAVE-UNIFORM (node is per-wave), so no divergence — just 8 gather
// loads in flight instead of 4. One 4-B packed load per lane per edge.
// ---------------------------------------------------------------------------
__global__ __launch_bounds__(256) void k_agg2(
    u32* Xpk, const int* __restrict__ row_ptr,
    const int* __restrict__ col_src, int n_nodes)
{
    int wid    = (blockIdx.x * blockDim.x + threadIdx.x) >> 6;
    int lane   = threadIdx.x & 63;
    int nwaves = (gridDim.x * blockDim.x) >> 6;
    for (int base = wid; base < n_nodes; base += 2 * nwaves) {
        const int nA = base;
        const int nB = base + nwaves;
        const bool hasB = nB < n_nodes;

        int eA = row_ptr[nA], endA = row_ptr[nA + 1];
        int eB = 0, endB = 0;
        if (hasB) { eB = row_ptr[nB]; endB = row_ptr[nB + 1]; }

        float accA = 0.f, accB = 0.f;
        while (true) {
            bool dA = (eA + 4 <= endA);
            bool dB = (eB + 4 <= endB);
            if (!dA && !dB) break;
            float a0 = 0.f, a1 = 0.f, a2 = 0.f, a3 = 0.f;
            float b0 = 0.f, b1 = 0.f, b2 = 0.f, b3 = 0.f;
            if (dA) {
                int s0 = col_src[eA], s1 = col_src[eA + 1];
                int s2 = col_src[eA + 2], s3 = col_src[eA + 3];
                a0 = unpackhl(Xpk[(size_t)s0 * 128 + 64 + lane]);
                a1 = unpackhl(Xpk[(size_t)s1 * 128 + 64 + lane]);
                a2 = unpackhl(Xpk[(size_t)s2 * 128 + 64 + lane]);
                a3 = unpackhl(Xpk[(size_t)s3 * 128 + 64 + lane]);
            }
            if (dB) {
                int s0 = col_src[eB], s1 = col_src[eB + 1];
                int s2 = col_src[eB + 2], s3 = col_src[eB + 3];
                b0 = unpackhl(Xpk[(size_t)s0 * 128 + 64 + lane]);
                b1 = unpackhl(Xpk[(size_t)s1 * 128 + 64 + lane]);
                b2 = unpackhl(Xpk[(size_t)s2 * 128 + 64 + lane]);
                b3 = unpackhl(Xpk[(size_t)s3 * 128 + 64 + lane]);
            }
            if (dA) { accA += (a0 + a1) + (a2 + a3); eA += 4; }
            if (dB) { accB += (b0 + b1) + (b2 + b3); eB += 4; }
        }
        for (; eA < endA; ++eA)
            accA += unpackhl(Xpk[(size_t)col_src[eA] * 128 + 64 + lane]);
        for (; eB < endB; ++eB)
            accB += unpackhl(Xpk[(size_t)col_src[eB] * 128 + 64 + lane]);

        Xpk[(size_t)nA * 128 + lane] = packhl(accA);
        if (hasB) Xpk[(size_t)nB * 128 + lane] = packhl(accB);
    }
}

// ---------------------------------------------------------------------------
// Wic[l][j][k] = sum_m w_ih[j][m] * gg_w[l][k][m]  (fp32 staging)
// ---------------------------------------------------------------------------
__global__ void k_wic(const float* __restrict__ gg_w, const float* __restrict__ w_ih,
                      float* __restrict__ Wic)
{
    int idx = blockIdx.x * blockDim.x + threadIdx.x;
    if (idx < NUM_LAYERS * 192 * 64) {
        int l = idx / (192 * 64);
        int j = (idx / 64) % 192;
        int k = idx % 64;
        const float* gw = gg_w + ((size_t)l * 64 + k) * 64;
        const float* wi = w_ih + (size_t)j * 64;
        float acc = 0.f;
#pragma unroll 4
        for (int m = 0; m < 64; ++m) acc = fmaf(wi[m], gw[m], acc);
        Wic[idx] = acc;
    }
}

// ---------------------------------------------------------------------------
// W' pack: [3][256][128] f16 hi/lo, SPLIT arrays. Rows 0-63: r; 64-127: z
// (both [Wic | whh]); 128-191: [Wic_n | 0]; 192-255: [0 | whh_n].
// ---------------------------------------------------------------------------
__global__ void k_wpack(const float* __restrict__ Wic, const float* __restrict__ whh,
                        u16* __restrict__ Wphi, u16* __restrict__ Wplo)
{
    int idx = blockIdx.x * 256 + threadIdx.x;
    if (idx >= NUM_LAYERS * 256 * 128) return;
    int l = idx / (256 * 128);
    int n = (idx / 128) & 255;
    int k = idx & 127;
    float v;
    if (n < 128)      v = (k < 64) ? Wic[((size_t)l * 192 + n) * 64 + k] : whh[(size_t)n * 64 + (k - 64)];
    else if (n < 192) v = (k < 64) ? Wic[((size_t)l * 192 + n) * 64 + k] : 0.f;
    else              v = (k < 64) ? 0.f : whh[(size_t)(n - 64) * 64 + (k - 64)];
    u16 hi = f2h(v);
    Wphi[idx] = hi;
    Wplo[idx] = f2h(v - h2f(hi));
}

// ---------------------------------------------------------------------------
// fused GRU v8b — r19-verified core + BATCHED B-loads. Evidence (r19/r20):
// MfmaUtil 9%, VALU 17%, HBM 7% at ~35 us/wave ≈ serial VMEM latency — the
// emitted code interleaved load->MFMA per tile, so each B-load stalls a full
// L2 round trip. Fix: per s-step, 3 batches of 4 tiles; each batch issues 8
// fragment loads (bh[4]/bl[4], static indices -> registers) BEFORE its 16
// MFMAs -> 8 loads in flight. Same ops, same per-acc order (bit-identical
// numerics). VGPR ~116 < 128 cap.
// ---------------------------------------------------------------------------
__global__ __launch_bounds__(256) void k_gru8(
    u32* Xpk,
    const u16* __restrict__ Wphi, const u16* __restrict__ Wplo,
    const float* __restrict__ b_ih, const float* __restrict__ b_hh, int n_nodes)
{
    const int l    = threadIdx.x & 63;
    const int wv   = threadIdx.x >> 6;
    const int base = blockIdx.x * 64 + wv * 16;
    if (base >= n_nodes) return;

    const int lrow = l & 15;
    const int lk   = (l >> 4) * 8;

    int arow = base + lrow;
    if (arow > n_nodes - 1) arow = n_nodes - 1;
    const u32* xp = Xpk + (size_t)arow * 128;

    f32x4 acc[16];
#pragma unroll
    for (int t = 0; t < 16; ++t) acc[t] = f32x4{0.f, 0.f, 0.f, 0.f};

#pragma unroll
    for (int s = 0; s < 4; ++s) {
        const uint4* pa = reinterpret_cast<const uint4*>(xp + s * 32 + lk);
        uint4 w0 = pa[0], w1 = pa[1];
        s16x8 p0 = __builtin_bit_cast(s16x8, w0);  // hi0,lo0,hi1,lo1,...
        s16x8 p1 = __builtin_bit_cast(s16x8, w1);
        s16x8 ahi = __builtin_shufflevector(p0, p1, 0, 2, 4, 6, 8, 10, 12, 14);
        s16x8 alo = __builtin_shufflevector(p0, p1, 1, 3, 5, 7, 9, 11, 13, 15);

        const int cb = (s < 2) ? 8 : 12;  // i_n tiles for k<64, h_n for k>=64
#pragma unroll
        for (int b = 0; b < 3; ++b) {
            const int t0 = (b == 0) ? 0 : (b == 1) ? 4 : cb;
            s16x8 bh[4], bl[4];
#pragma unroll
            for (int i = 0; i < 4; ++i) {
                const size_t woff = (size_t)((t0 + i) * 16 + lrow) * 128 + s * 32 + lk;
                bh[i] = *reinterpret_cast<const s16x8*>(Wphi + woff);
                bl[i] = *reinterpret_cast<const s16x8*>(Wplo + woff);
            }
#pragma unroll
            for (int i = 0; i < 4; ++i) {
                acc[t0 + i] = mfma_f16(ahi, bh[i], acc[t0 + i]);
                acc[t0 + i] = mfma_f16(alo, bh[i], acc[t0 + i]);
                acc[t0 + i] = mfma_f16(ahi, bl[i], acc[t0 + i]);
                acc[t0 + i] = mfma_f16(alo, bl[i], acc[t0 + i]);
            }
        }
    }

    const int quarter = l >> 4;
    const int c = lrow;
#pragma unroll
    for (int r = 0; r < 4; ++r) {
        int m = base + quarter * 4 + r;
        if (m < n_nodes) {
            u32* hp = Xpk + (size_t)m * 128 + 64;
#pragma unroll
            for (int q = 0; q < 4; ++q) {
                int j = q * 16 + c;
                float rv = acc[q][r]      + b_ih[j]       + b_hh[j];
                float zv = acc[4 + q][r]  + b_ih[64 + j]  + b_hh[64 + j];
                float iv = acc[8 + q][r]  + b_ih[128 + j];
                float hv = acc[12 + q][r] + b_hh[128 + j];
                rv = 1.f / (1.f + __expf(-rv));
                zv = 1.f / (1.f + __expf(-zv));
                float x2 = iv + rv * hv;
                float nn = 1.f - 2.f / (__expf(2.f * x2) + 1.f);  // tanh, inf-safe
                float hold = unpackhl(hp[j]);
                hp[j] = packhl((1.f - zv) * nn + zv * hold);
            }
        }
    }
}

// ---------------------------------------------------------------------------
// out = softmax(h @ w2.T + b2); h read from packed Xpk h-half
// ---------------------------------------------------------------------------
__global__ __launch_bounds__(256) void k_out(
    const u32* __restrict__ Xpk, const float* __restrict__ w2,
    const float* __restrict__ b2, float* __restrict__ out, int n_nodes)
{
    const int tid = threadIdx.x, lane = tid & 63;
    float wreg[64];
    float bias = 0.f;
    if (lane < NCLASS) {
#pragma unroll
        for (int k = 0; k < 64; k += 4) {
            float4 v = *reinterpret_cast<const float4*>(&w2[lane * HID + k]);
            wreg[k] = v.x; wreg[k + 1] = v.y; wreg[k + 2] = v.z; wreg[k + 3] = v.w;
        }
        bias = b2[lane];
    } else {
#pragma unroll
        for (int k = 0; k < 64; ++k) wreg[k] = 0.f;
    }
    int wid    = (blockIdx.x * blockDim.x + tid) >> 6;
    int nwaves = (gridDim.x * blockDim.x) >> 6;
    for (int node = wid; node < n_nodes; node += nwaves) {
        const uint4* p4 = reinterpret_cast<const uint4*>(Xpk + (size_t)node * 128 + 64);
        float a0 = bias, a1 = 0.f, a2 = 0.f, a3 = 0.f;
#pragma unroll
        for (int kq = 0; kq < 16; ++kq) {
            uint4 v = p4[kq];
            a0 = fmaf(unpackhl(v.x), wreg[4 * kq + 0], a0);
            a1 = fmaf(unpackhl(v.y), wreg[4 * kq + 1], a1);
            a2 = fmaf(unpackhl(v.z), wreg[4 * kq + 2], a2);
            a3 = fmaf(unpackhl(v.w), wreg[4 * kq + 3], a3);
        }
        float lg = (lane < NCLASS) ? (a0 + a1) + (a2 + a3) : -INFINITY;
        float m = lg;
#pragma unroll
        for (int off = 32; off > 0; off >>= 1) m = fmaxf(m, __shfl_xor(m, off, 64));
        float p = (lane < NCLASS) ? __expf(lg - m) : 0.f;
        float s = p;
#pragma unroll
        for (int off = 32; off > 0; off >>= 1) s += __shfl_xor(s, off, 64);
        if (lane < NCLASS) out[(size_t)node * NCLASS + lane] = p / s;
    }
}

// ---------------------------------------------------------------------------
extern "C" void kernel_launch(void* const* d_in, const int* in_sizes, int n_in,
                              void* d_out, int out_size, void* d_ws, size_t ws_size,
                              hipStream_t stream)
{
    const float* x    = (const float*)d_in[0];
    const int*   ei   = (const int*)d_in[1];    // int32 per harness contract
    const float* w1   = (const float*)d_in[2];
    const float* b1   = (const float*)d_in[3];
    const float* gg_w = (const float*)d_in[4];
    const float* w_ih = (const float*)d_in[5];
    const float* w_hh = (const float*)d_in[6];
    const float* b_ih = (const float*)d_in[7];
    const float* b_hh = (const float*)d_in[8];
    const float* w2   = (const float*)d_in[9];
    const float* b2   = (const float*)d_in[10];
    float*       out  = (float*)d_out;

    const int n = in_sizes[0] / NFEAT;   // 200000
    const int E = in_sizes[1] / 2;       // 1200000

    // workspace carve (~110 MB, proven envelope), 256-B aligned slots
    char* ws0 = (char*)d_ws;
    char* ws  = ws0;
    auto carve = [&](size_t bytes) {
        char* p = ws;
        ws += (bytes + 255) & ~(size_t)255;
        return p;
    };
    u32*   Xpk     = (u32*)carve((size_t)n * 128 * 4);               // 102.4 MB
    float* Wic     = (float*)carve((size_t)NUM_LAYERS * 192 * 64 * 4);
    u16*   Wphi    = (u16*)carve((size_t)NUM_LAYERS * 256 * 128 * 2);
    u16*   Wplo    = (u16*)carve((size_t)NUM_LAYERS * 256 * 128 * 2);
    int*   row_ptr = (int*)carve((size_t)(n + 1) * 4);
    int*   col_src = (int*)carve((size_t)E * 4);
    int*   cnt     = (int*)carve((size_t)n * 4);
    int*   cursor  = (int*)carve((size_t)n * 4);
    int*   btot    = (int*)carve(8192);

    const int nb = (n + SCAN_C - 1) / SCAN_C;

    hipMemsetAsync(cnt, 0, (size_t)n * 4, stream);
    k_wic<<<(NUM_LAYERS * 192 * 64 + 255) / 256, 256, 0, stream>>>(gg_w, w_ih, Wic);
    k_wpack<<<(NUM_LAYERS * 256 * 128 + 255) / 256, 256, 0, stream>>>(Wic, w_hh, Wphi, Wplo);
    k_lin1<<<2048, 256, 0, stream>>>(x, w1, b1, Xpk, n);
    k_hist<<<(E + 255) / 256, 256, 0, stream>>>(ei, cnt, E);
    k_scan1<<<nb, 512, 0, stream>>>(cnt, btot, n);
    k_scan2<<<1, 1024, 0, stream>>>(btot, nb);
    k_scan3<<<nb, 512, 0, stream>>>(cnt, btot, row_ptr, cursor, n);
    k_fill<<<(E + 255) / 256, 256, 0, stream>>>(ei, cursor, col_src, E);

    const int gblocks = (n + 63) / 64;  // 3125
    for (int l = 0; l < NUM_LAYERS; ++l) {
        k_agg2<<<2048, 256, 0, stream>>>(Xpk, row_ptr, col_src, n);
        k_gru8<<<gblocks, 256, 0, stream>>>(Xpk,
                                            Wphi + (size_t)l * 256 * 128,
                                            Wplo + (size_t)l * 256 * 128,
                                            b_ih, b_hh, n);
    }
    k_out<<<2048, 256, 0, stream>>>(Xpk, w2, b2, out, n);
}

// Round 23
// 862.251 us; speedup vs baseline: 1.5144x; 1.3013x over previous
//
#include <hip/hip_runtime.h>
#include <hip/hip_bf16.h>

#define NFEAT 256
#define HID 64
#define NCLASS 40
#define NUM_LAYERS 3

typedef unsigned short u16;
typedef unsigned int   u32;
typedef float    f32x4 __attribute__((ext_vector_type(4)));
typedef short    s16x8 __attribute__((ext_vector_type(8)));
typedef _Float16 h16x8 __attribute__((ext_vector_type(8)));

// fp16 hi/lo split: hi = (f16)f, lo = (f16)(f - hi) -> ~22-23 mantissa bits
__device__ __forceinline__ u16 f2h(float f) {
    _Float16 h = (_Float16)f;
    return __builtin_bit_cast(u16, h);
}
__device__ __forceinline__ float h2f(u16 s) {
    return (float)__builtin_bit_cast(_Float16, s);
}
__device__ __forceinline__ u32 packhl(float f) {
    u16 hi = f2h(f);
    u16 lo = f2h(f - h2f(hi));
    return (u32)hi | ((u32)lo << 16);
}
__device__ __forceinline__ float unpackhl(u32 v) {
    return h2f((u16)v) + h2f((u16)(v >> 16));
}

// BUILTIN MFMA (r18/r19 lesson: raw inline-asm MFMA is opaque to the hazard
// recognizer; the builtin gets compiler-inserted wait states. r19-verified.)
__device__ __forceinline__ f32x4 mfma_f16(s16x8 a, s16x8 b, f32x4 c) {
    return __builtin_amdgcn_mfma_f32_16x16x32_f16(
        __builtin_bit_cast(h16x8, a), __builtin_bit_cast(h16x8, b), c, 0, 0, 0);
}

// ---------------------------------------------------------------------------
// lin1: h = relu(x @ w1.T + b1) -> packed f16 hi|lo u32 into Xpk[:,64:128]
// ---------------------------------------------------------------------------
__global__ __launch_bounds__(256) void k_lin1(
    const float* __restrict__ x, const float* __restrict__ w1,
    const float* __restrict__ b1, u32* Xpk, int n_nodes)
{
    __shared__ float xs[8][NFEAT];
    __shared__ float part[4][8][HID];
    const int tid  = threadIdx.x;
    const int wave = tid >> 6;
    const int lane = tid & 63;

    float wreg[64];
#pragma unroll
    for (int k = 0; k < 64; k += 4) {
        float4 v = *reinterpret_cast<const float4*>(&w1[lane * NFEAT + wave * 64 + k]);
        wreg[k] = v.x; wreg[k + 1] = v.y; wreg[k + 2] = v.z; wreg[k + 3] = v.w;
    }

    const int nbatch = (n_nodes + 7) >> 3;
    for (int batch = blockIdx.x; batch < nbatch; batch += gridDim.x) {
        const int n0 = batch * 8;
        {
            const float4* xg = reinterpret_cast<const float4*>(x + (size_t)n0 * NFEAT);
            float4* xsv = reinterpret_cast<float4*>(&xs[0][0]);
#pragma unroll
            for (int i = 0; i < 2; ++i) {
                int idx  = tid + i * 256;
                int node = n0 + (idx >> 6);
                xsv[idx] = (node < n_nodes) ? xg[idx] : make_float4(0.f, 0.f, 0.f, 0.f);
            }
        }
        __syncthreads();
        for (int nl = 0; nl < 8; ++nl) {
            const float4* xrow = reinterpret_cast<const float4*>(&xs[nl][wave * 64]);
            float a0 = 0.f, a1 = 0.f, a2 = 0.f, a3 = 0.f;
#pragma unroll
            for (int kq = 0; kq < 16; ++kq) {
                float4 v = xrow[kq];
                a0 = fmaf(v.x, wreg[4 * kq + 0], a0);
                a1 = fmaf(v.y, wreg[4 * kq + 1], a1);
                a2 = fmaf(v.z, wreg[4 * kq + 2], a2);
                a3 = fmaf(v.w, wreg[4 * kq + 3], a3);
            }
            part[wave][nl][lane] = (a0 + a1) + (a2 + a3);
        }
        __syncthreads();
#pragma unroll
        for (int i = 0; i < 2; ++i) {
            int o = tid + i * 256;
            int nl = o >> 6, j = o & 63;
            int node = n0 + nl;
            if (node < n_nodes) {
                float v = part[0][nl][j] + part[1][nl][j] + part[2][nl][j] + part[3][nl][j]
                          + b1[j];
                Xpk[(size_t)node * 128 + 64 + j] = packhl(fmaxf(v, 0.f));
            }
        }
        __syncthreads();
    }
}

// ---------------------------------------------------------------------------
// CSR build (int32 edge_index)
// ---------------------------------------------------------------------------
__global__ void k_hist(const int* __restrict__ ei, int* __restrict__ cnt, int E)
{
    int i = blockIdx.x * blockDim.x + threadIdx.x;
    if (i < E) atomicAdd(&cnt[ei[E + i]], 1);
}

#define SCAN_C 2048
__global__ __launch_bounds__(512) void k_scan1(const int* __restrict__ cnt,
                                               int* __restrict__ btot, int n)
{
    __shared__ int sd[512];
    int b = blockIdx.x, t = threadIdx.x;
    int base = b * SCAN_C + t * 4;
    int s = 0;
#pragma unroll
    for (int i = 0; i < 4; ++i) { int idx = base + i; if (idx < n) s += cnt[idx]; }
    sd[t] = s; __syncthreads();
    for (int off = 256; off > 0; off >>= 1) {
        if (t < off) sd[t] += sd[t + off];
        __syncthreads();
    }
    if (t == 0) btot[b] = sd[0];
}

__global__ __launch_bounds__(1024) void k_scan2(int* __restrict__ btot, int nb)
{
    __shared__ int sd[1024];
    int t = threadIdx.x;
    int v = (t < nb) ? btot[t] : 0;
    sd[t] = v; __syncthreads();
    for (int off = 1; off < 1024; off <<= 1) {
        int x = sd[t];
        int add = (t >= off) ? sd[t - off] : 0;
        __syncthreads();
        sd[t] = x + add;
        __syncthreads();
    }
    if (t < nb) btot[t] = sd[t] - v;  // exclusive
}

__global__ __launch_bounds__(512) void k_scan3(const int* __restrict__ cnt,
                                               const int* __restrict__ btot,
                                               int* __restrict__ row_ptr,
                                               int* __restrict__ cursor, int n)
{
    __shared__ int sth[512];
    int b = blockIdx.x, t = threadIdx.x;
    int base = b * SCAN_C + t * 4;
    int v[4]; int s = 0;
#pragma unroll
    for (int i = 0; i < 4; ++i) { int idx = base + i; v[i] = (idx < n) ? cnt[idx] : 0; s += v[i]; }
    sth[t] = s; __syncthreads();
    int mine = s;
    for (int off = 1; off < 512; off <<= 1) {
        int x = sth[t];
        int add = (t >= off) ? sth[t - off] : 0;
        __syncthreads();
        sth[t] = x + add;
        __syncthreads();
    }
    int carry = btot[b] + (sth[t] - mine);
#pragma unroll
    for (int i = 0; i < 4; ++i) {
        int idx = base + i;
        if (idx < n) {
            row_ptr[idx] = carry;
            cursor[idx]  = carry;
            carry += v[i];
            if (idx == n - 1) row_ptr[n] = carry;  // = E
        }
    }
}

__global__ void k_fill(const int* __restrict__ ei, int* __restrict__ cursor,
                       int* __restrict__ col_src, int E)
{
    int i = blockIdx.x * blockDim.x + threadIdx.x;
    if (i < E) {
        int dst = ei[E + i];
        int p = atomicAdd(&cursor[dst], 1);
        col_src[p] = ei[i];
    }
}

// ---------------------------------------------------------------------------
// aggregation v4: 2-node interleave (wave-uniform branches) — 8 gather loads
// in flight. One 4-B packed load per lane per edge. fp32 accumulation.
// ---------------------------------------------------------------------------
__global__ __launch_bounds__(256) void k_agg2(
    u32* Xpk, const int* __restrict__ row_ptr,
    const int* __restrict__ col_src, int n_nodes)
{
    int wid    = (blockIdx.x * blockDim.x + threadIdx.x) >> 6;
    int lane   = threadIdx.x & 63;
    int nwaves = (gridDim.x * blockDim.x) >> 6;
    for (int base = wid; base < n_nodes; base += 2 * nwaves) {
        const int nA = base;
        const int nB = base + nwaves;
        const bool hasB = nB < n_nodes;

        int eA = row_ptr[nA], endA = row_ptr[nA + 1];
        int eB = 0, endB = 0;
        if (hasB) { eB = row_ptr[nB]; endB = row_ptr[nB + 1]; }

        float accA = 0.f, accB = 0.f;
        while (true) {
            bool dA = (eA + 4 <= endA);
            bool dB = (eB + 4 <= endB);
            if (!dA && !dB) break;
            float a0 = 0.f, a1 = 0.f, a2 = 0.f, a3 = 0.f;
            float b0 = 0.f, b1 = 0.f, b2 = 0.f, b3 = 0.f;
            if (dA) {
                int s0 = col_src[eA], s1 = col_src[eA + 1];
                int s2 = col_src[eA + 2], s3 = col_src[eA + 3];
                a0 = unpackhl(Xpk[(size_t)s0 * 128 + 64 + lane]);
                a1 = unpackhl(Xpk[(size_t)s1 * 128 + 64 + lane]);
                a2 = unpackhl(Xpk[(size_t)s2 * 128 + 64 + lane]);
                a3 = unpackhl(Xpk[(size_t)s3 * 128 + 64 + lane]);
            }
            if (dB) {
                int s0 = col_src[eB], s1 = col_src[eB + 1];
                int s2 = col_src[eB + 2], s3 = col_src[eB + 3];
                b0 = unpackhl(Xpk[(size_t)s0 * 128 + 64 + lane]);
                b1 = unpackhl(Xpk[(size_t)s1 * 128 + 64 + lane]);
                b2 = unpackhl(Xpk[(size_t)s2 * 128 + 64 + lane]);
                b3 = unpackhl(Xpk[(size_t)s3 * 128 + 64 + lane]);
            }
            if (dA) { accA += (a0 + a1) + (a2 + a3); eA += 4; }
            if (dB) { accB += (b0 + b1) + (b2 + b3); eB += 4; }
        }
        for (; eA < endA; ++eA)
            accA += unpackhl(Xpk[(size_t)col_src[eA] * 128 + 64 + lane]);
        for (; eB < endB; ++eB)
            accB += unpackhl(Xpk[(size_t)col_src[eB] * 128 + 64 + lane]);

        Xpk[(size_t)nA * 128 + lane] = packhl(accA);
        if (hasB) Xpk[(size_t)nB * 128 + lane] = packhl(accB);
    }
}

// ---------------------------------------------------------------------------
// Wic[l][j][k] = sum_m w_ih[j][m] * gg_w[l][k][m]  (fp32 staging)
// ---------------------------------------------------------------------------
__global__ void k_wic(const float* __restrict__ gg_w, const float* __restrict__ w_ih,
                      float* __restrict__ Wic)
{
    int idx = blockIdx.x * blockDim.x + threadIdx.x;
    if (idx < NUM_LAYERS * 192 * 64) {
        int l = idx / (192 * 64);
        int j = (idx / 64) % 192;
        int k = idx % 64;
        const float* gw = gg_w + ((size_t)l * 64 + k) * 64;
        const float* wi = w_ih + (size_t)j * 64;
        float acc = 0.f;
#pragma unroll 4
        for (int m = 0; m < 64; ++m) acc = fmaf(wi[m], gw[m], acc);
        Wic[idx] = acc;
    }
}

// ---------------------------------------------------------------------------
// W' pack: [3][256][128] f16 hi/lo, SPLIT arrays. Rows 0-63: r; 64-127: z
// (both [Wic | whh]); 128-191: [Wic_n | 0]; 192-255: [0 | whh_n].
// ---------------------------------------------------------------------------
__global__ void k_wpack(const float* __restrict__ Wic, const float* __restrict__ whh,
                        u16* __restrict__ Wphi, u16* __restrict__ Wplo)
{
    int idx = blockIdx.x * 256 + threadIdx.x;
    if (idx >= NUM_LAYERS * 256 * 128) return;
    int l = idx / (256 * 128);
    int n = (idx / 128) & 255;
    int k = idx & 127;
    float v;
    if (n < 128)      v = (k < 64) ? Wic[((size_t)l * 192 + n) * 64 + k] : whh[(size_t)n * 64 + (k - 64)];
    else if (n < 192) v = (k < 64) ? Wic[((size_t)l * 192 + n) * 64 + k] : 0.f;
    else              v = (k < 64) ? 0.f : whh[(size_t)(n - 64) * 64 + (k - 64)];
    u16 hi = f2h(v);
    Wphi[idx] = hi;
    Wplo[idx] = f2h(v - h2f(hi));
}

// ---------------------------------------------------------------------------
// fused GRU v10 — r19-verified core + WEIGHTS IN LDS.
// Evidence (r19-r22): gru pinned at ~175 us, MFMA ~19 us, VALU ~30 us; the
// rest is B-fragment L2 latency, with every wave duplicating ~98 KB of
// weight-fragment reads (4.8 MB L2 traffic per CU for a 131 KB set).
// Fix: block = 512 thr (8 waves x 16 nodes = 128 nodes); stage the layer's
// Wphi/Wplo into LDS once (131 KB -> padded [256][136] u16, row stride
// 272 B -> bank = 4*row mod 32 -> 16 consecutive rows = 2-way = free, m136),
// one barrier, then B-frags via ds_read_b128 (~12 cyc vs ~200 cyc L2).
// 139 KB LDS -> 1 block/CU, 2 waves/SIMD. Numerics bit-identical to r19.
// ---------------------------------------------------------------------------
#define WPAD 136
__global__ __launch_bounds__(512) void k_gru10(
    u32* Xpk,
    const u16* __restrict__ Wphi, const u16* __restrict__ Wplo,
    const float* __restrict__ b_ih, const float* __restrict__ b_hh, int n_nodes)
{
    __shared__ u16 wlh[256][WPAD];  // 69.6 KB
    __shared__ u16 wll[256][WPAD];  // 69.6 KB

    const int tid = threadIdx.x;

    // cooperative staging: 4096 uint4 per array (coalesced 16-B loads)
    {
        const uint4* gh = reinterpret_cast<const uint4*>(Wphi);
        const uint4* gl = reinterpret_cast<const uint4*>(Wplo);
#pragma unroll
        for (int i = 0; i < 8; ++i) {
            int e   = tid + i * 512;          // 0..4095
            int row = e >> 4;
            int c8  = (e & 15) * 8;           // u16 col
            *reinterpret_cast<uint4*>(&wlh[row][c8]) = gh[e];
            *reinterpret_cast<uint4*>(&wll[row][c8]) = gl[e];
        }
    }
    __syncthreads();

    const int l    = tid & 63;
    const int wv   = tid >> 6;                 // 0..7
    const int base = blockIdx.x * 128 + wv * 16;
    if (base >= n_nodes) return;

    const int lrow = l & 15;
    const int lk   = (l >> 4) * 8;

    int arow = base + lrow;
    if (arow > n_nodes - 1) arow = n_nodes - 1;
    const u32* xp = Xpk + (size_t)arow * 128;

    f32x4 acc[16];
#pragma unroll
    for (int t = 0; t < 16; ++t) acc[t] = f32x4{0.f, 0.f, 0.f, 0.f};

#pragma unroll
    for (int s = 0; s < 4; ++s) {
        const uint4* pa = reinterpret_cast<const uint4*>(xp + s * 32 + lk);
        uint4 w0 = pa[0], w1 = pa[1];
        s16x8 p0 = __builtin_bit_cast(s16x8, w0);  // hi0,lo0,hi1,lo1,...
        s16x8 p1 = __builtin_bit_cast(s16x8, w1);
        s16x8 ahi = __builtin_shufflevector(p0, p1, 0, 2, 4, 6, 8, 10, 12, 14);
        s16x8 alo = __builtin_shufflevector(p0, p1, 1, 3, 5, 7, 9, 11, 13, 15);
#pragma unroll
        for (int t = 0; t < 16; ++t) {
            const bool valid = (t < 8) || (t < 12 ? (s < 2) : (s >= 2));
            if (!valid) continue;  // compile-time after unroll
            const int wr = t * 16 + lrow;
            const int wc = s * 32 + lk;
            s16x8 bhi = *reinterpret_cast<const s16x8*>(&wlh[wr][wc]);
            s16x8 blo = *reinterpret_cast<const s16x8*>(&wll[wr][wc]);
            acc[t] = mfma_f16(ahi, bhi, acc[t]);
            acc[t] = mfma_f16(alo, bhi, acc[t]);
            acc[t] = mfma_f16(ahi, blo, acc[t]);
            acc[t] = mfma_f16(alo, blo, acc[t]);
        }
    }

    const int quarter = l >> 4;
    const int c = lrow;
#pragma unroll
    for (int r = 0; r < 4; ++r) {
        int m = base + quarter * 4 + r;
        if (m < n_nodes) {
            u32* hp = Xpk + (size_t)m * 128 + 64;
#pragma unroll
            for (int q = 0; q < 4; ++q) {
                int j = q * 16 + c;
                float rv = acc[q][r]      + b_ih[j]       + b_hh[j];
                float zv = acc[4 + q][r]  + b_ih[64 + j]  + b_hh[64 + j];
                float iv = acc[8 + q][r]  + b_ih[128 + j];
                float hv = acc[12 + q][r] + b_hh[128 + j];
                rv = 1.f / (1.f + __expf(-rv));
                zv = 1.f / (1.f + __expf(-zv));
                float x2 = iv + rv * hv;
                float nn = 1.f - 2.f / (__expf(2.f * x2) + 1.f);  // tanh, inf-safe
                float hold = unpackhl(hp[j]);
                hp[j] = packhl((1.f - zv) * nn + zv * hold);
            }
        }
    }
}

// ---------------------------------------------------------------------------
// out = softmax(h @ w2.T + b2); h read from packed Xpk h-half
// ---------------------------------------------------------------------------
__global__ __launch_bounds__(256) void k_out(
    const u32* __restrict__ Xpk, const float* __restrict__ w2,
    const float* __restrict__ b2, float* __restrict__ out, int n_nodes)
{
    const int tid = threadIdx.x, lane = tid & 63;
    float wreg[64];
    float bias = 0.f;
    if (lane < NCLASS) {
#pragma unroll
        for (int k = 0; k < 64; k += 4) {
            float4 v = *reinterpret_cast<const float4*>(&w2[lane * HID + k]);
            wreg[k] = v.x; wreg[k + 1] = v.y; wreg[k + 2] = v.z; wreg[k + 3] = v.w;
        }
        bias = b2[lane];
    } else {
#pragma unroll
        for (int k = 0; k < 64; ++k) wreg[k] = 0.f;
    }
    int wid    = (blockIdx.x * blockDim.x + tid) >> 6;
    int nwaves = (gridDim.x * blockDim.x) >> 6;
    for (int node = wid; node < n_nodes; node += nwaves) {
        const uint4* p4 = reinterpret_cast<const uint4*>(Xpk + (size_t)node * 128 + 64);
        float a0 = bias, a1 = 0.f, a2 = 0.f, a3 = 0.f;
#pragma unroll
        for (int kq = 0; kq < 16; ++kq) {
            uint4 v = p4[kq];
            a0 = fmaf(unpackhl(v.x), wreg[4 * kq + 0], a0);
            a1 = fmaf(unpackhl(v.y), wreg[4 * kq + 1], a1);
            a2 = fmaf(unpackhl(v.z), wreg[4 * kq + 2], a2);
            a3 = fmaf(unpackhl(v.w), wreg[4 * kq + 3], a3);
        }
        float lg = (lane < NCLASS) ? (a0 + a1) + (a2 + a3) : -INFINITY;
        float m = lg;
#pragma unroll
        for (int off = 32; off > 0; off >>= 1) m = fmaxf(m, __shfl_xor(m, off, 64));
        float p = (lane < NCLASS) ? __expf(lg - m) : 0.f;
        float s = p;
#pragma unroll
        for (int off = 32; off > 0; off >>= 1) s += __shfl_xor(s, off, 64);
        if (lane < NCLASS) out[(size_t)node * NCLASS + lane] = p / s;
    }
}

// ---------------------------------------------------------------------------
extern "C" void kernel_launch(void* const* d_in, const int* in_sizes, int n_in,
                              void* d_out, int out_size, void* d_ws, size_t ws_size,
                              hipStream_t stream)
{
    const float* x    = (const float*)d_in[0];
    const int*   ei   = (const int*)d_in[1];    // int32 per harness contract
    const float* w1   = (const float*)d_in[2];
    const float* b1   = (const float*)d_in[3];
    const float* gg_w = (const float*)d_in[4];
    const float* w_ih = (const float*)d_in[5];
    const float* w_hh = (const float*)d_in[6];
    const float* b_ih = (const float*)d_in[7];
    const float* b_hh = (const float*)d_in[8];
    const float* w2   = (const float*)d_in[9];
    const float* b2   = (const float*)d_in[10];
    float*       out  = (float*)d_out;

    const int n = in_sizes[0] / NFEAT;   // 200000
    const int E = in_sizes[1] / 2;       // 1200000

    // workspace carve (~110 MB, proven envelope), 256-B aligned slots
    char* ws0 = (char*)d_ws;
    char* ws  = ws0;
    auto carve = [&](size_t bytes) {
        char* p = ws;
        ws += (bytes + 255) & ~(size_t)255;
        return p;
    };
    u32*   Xpk     = (u32*)carve((size_t)n * 128 * 4);               // 102.4 MB
    float* Wic     = (float*)carve((size_t)NUM_LAYERS * 192 * 64 * 4);
    u16*   Wphi    = (u16*)carve((size_t)NUM_LAYERS * 256 * 128 * 2);
    u16*   Wplo    = (u16*)carve((size_t)NUM_LAYERS * 256 * 128 * 2);
    int*   row_ptr = (int*)carve((size_t)(n + 1) * 4);
    int*   col_src = (int*)carve((size_t)E * 4);
    int*   cnt     = (int*)carve((size_t)n * 4);
    int*   cursor  = (int*)carve((size_t)n * 4);
    int*   btot    = (int*)carve(8192);

    const int nb = (n + SCAN_C - 1) / SCAN_C;

    hipMemsetAsync(cnt, 0, (size_t)n * 4, stream);
    k_wic<<<(NUM_LAYERS * 192 * 64 + 255) / 256, 256, 0, stream>>>(gg_w, w_ih, Wic);
    k_wpack<<<(NUM_LAYERS * 256 * 128 + 255) / 256, 256, 0, stream>>>(Wic, w_hh, Wphi, Wplo);
    k_lin1<<<2048, 256, 0, stream>>>(x, w1, b1, Xpk, n);
    k_hist<<<(E + 255) / 256, 256, 0, stream>>>(ei, cnt, E);
    k_scan1<<<nb, 512, 0, stream>>>(cnt, btot, n);
    k_scan2<<<1, 1024, 0, stream>>>(btot, nb);
    k_scan3<<<nb, 512, 0, stream>>>(cnt, btot, row_ptr, cursor, n);
    k_fill<<<(E + 255) / 256, 256, 0, stream>>>(ei, cursor, col_src, E);

    const int gblocks = (n + 127) / 128;  // 1563
    for (int l = 0; l < NUM_LAYERS; ++l) {
        k_agg2<<<2048, 256, 0, stream>>>(Xpk, row_ptr, col_src, n);
        k_gru10<<<gblocks, 512, 0, stream>>>(Xpk,
                                             Wphi + (size_t)l * 256 * 128,
                                             Wplo + (size_t)l * 256 * 128,
                                             b_ih, b_hh, n);
    }
    k_out<<<2048, 256, 0, stream>>>(Xpk, w2, b2, out, n);
}

// Round 24
// 789.237 us; speedup vs baseline: 1.6545x; 1.0925x over previous
//
#include <hip/hip_runtime.h>
#include <hip/hip_bf16.h>

#define NFEAT 256
#define HID 64
#define NCLASS 40
#define NUM_LAYERS 3

typedef unsigned short u16;
typedef unsigned int   u32;
typedef float    f32x4 __attribute__((ext_vector_type(4)));
typedef short    s16x8 __attribute__((ext_vector_type(8)));
typedef _Float16 h16x8 __attribute__((ext_vector_type(8)));

// fp16 hi/lo split: hi = (f16)f, lo = (f16)(f - hi) -> ~22-23 mantissa bits
__device__ __forceinline__ u16 f2h(float f) {
    _Float16 h = (_Float16)f;
    return __builtin_bit_cast(u16, h);
}
__device__ __forceinline__ float h2f(u16 s) {
    return (float)__builtin_bit_cast(_Float16, s);
}
__device__ __forceinline__ u32 packhl(float f) {
    u16 hi = f2h(f);
    u16 lo = f2h(f - h2f(hi));
    return (u32)hi | ((u32)lo << 16);
}
__device__ __forceinline__ float unpackhl(u32 v) {
    return h2f((u16)v) + h2f((u16)(v >> 16));
}

// BUILTIN MFMA (r18/r19 lesson: raw inline-asm MFMA is opaque to the hazard
// recognizer; the builtin gets compiler-inserted wait states. r19-verified.)
__device__ __forceinline__ f32x4 mfma_f16(s16x8 a, s16x8 b, f32x4 c) {
    return __builtin_amdgcn_mfma_f32_16x16x32_f16(
        __builtin_bit_cast(h16x8, a), __builtin_bit_cast(h16x8, b), c, 0, 0, 0);
}

// ---------------------------------------------------------------------------
// w1 pack: [64][256] fp32 -> f16 hi/lo split arrays
// ---------------------------------------------------------------------------
__global__ void k_w1pack(const float* __restrict__ w1,
                         u16* __restrict__ W1h, u16* __restrict__ W1l)
{
    int idx = blockIdx.x * 256 + threadIdx.x;
    if (idx >= 64 * 256) return;
    float v = w1[idx];
    u16 hi = f2h(v);
    W1h[idx] = hi;
    W1l[idx] = f2h(v - h2f(hi));
}

// ---------------------------------------------------------------------------
// lin1 v2 (MFMA): h = relu(x @ w1.T + b1) -> packed u32 into Xpk[:,64:128].
// r23 evidence: VALU-version ran at 160 us, VALUBusy 63% (VALU-bound, matrix
// units idle). This uses the r19-verified fp16 hi/lo 4-term MFMA core:
// block 512 (8 waves x 16 nodes); w1 hi/lo staged in LDS [64][264] u16
// (row stride 528 B -> bank = 4*row mod 32, same proven-conflict-free math
// as gru10); A-frags = x fp32 loads converted to hi/lo f16 in-register.
// 128 MFMA/wave; exact products, fp32 acc -> error ~2^-22 (fp32-like).
// ---------------------------------------------------------------------------
#define W1PAD 264
__global__ __launch_bounds__(512) void k_lin2(
    const float* __restrict__ x,
    const u16* __restrict__ W1h, const u16* __restrict__ W1l,
    const float* __restrict__ b1, u32* Xpk, int n_nodes)
{
    __shared__ u16 w1h[64][W1PAD];  // 33.8 KB
    __shared__ u16 w1l[64][W1PAD];  // 33.8 KB

    const int tid = threadIdx.x;
    // stage w1 hi/lo: 2048 uint4 each (4 per thread), coalesced
    {
        const uint4* gh = reinterpret_cast<const uint4*>(W1h);
        const uint4* gl = reinterpret_cast<const uint4*>(W1l);
#pragma unroll
        for (int i = 0; i < 4; ++i) {
            int e   = tid + i * 512;   // 0..2047
            int row = e >> 5;          // 32 uint4 per 256-u16 row
            int c8  = (e & 31) * 8;
            *reinterpret_cast<uint4*>(&w1h[row][c8]) = gh[e];
            *reinterpret_cast<uint4*>(&w1l[row][c8]) = gl[e];
        }
    }
    __syncthreads();

    const int l    = tid & 63;
    const int wv   = tid >> 6;
    const int base = blockIdx.x * 128 + wv * 16;
    if (base >= n_nodes) return;

    const int lrow = l & 15;
    const int lk   = (l >> 4) * 8;

    int arow = base + lrow;
    if (arow > n_nodes - 1) arow = n_nodes - 1;
    const float* xr = x + (size_t)arow * NFEAT;

    f32x4 acc[4];
#pragma unroll
    for (int t = 0; t < 4; ++t) acc[t] = f32x4{0.f, 0.f, 0.f, 0.f};

#pragma unroll
    for (int s = 0; s < 8; ++s) {
        const float4* pa = reinterpret_cast<const float4*>(xr + s * 32 + lk);
        float4 f0 = pa[0], f1 = pa[1];
        const float fv[8] = {f0.x, f0.y, f0.z, f0.w, f1.x, f1.y, f1.z, f1.w};
        s16x8 ahi, alo;
#pragma unroll
        for (int i2 = 0; i2 < 8; ++i2) {
            u16 hi = f2h(fv[i2]);
            u16 lo = f2h(fv[i2] - h2f(hi));
            ahi[i2] = (short)hi;
            alo[i2] = (short)lo;
        }
#pragma unroll
        for (int t = 0; t < 4; ++t) {
            s16x8 bhi = *reinterpret_cast<const s16x8*>(&w1h[t * 16 + lrow][s * 32 + lk]);
            s16x8 blo = *reinterpret_cast<const s16x8*>(&w1l[t * 16 + lrow][s * 32 + lk]);
            acc[t] = mfma_f16(ahi, bhi, acc[t]);
            acc[t] = mfma_f16(alo, bhi, acc[t]);
            acc[t] = mfma_f16(ahi, blo, acc[t]);
            acc[t] = mfma_f16(alo, blo, acc[t]);
        }
    }

    const int quarter = l >> 4;
    const int c = lrow;
#pragma unroll
    for (int r = 0; r < 4; ++r) {
        int m = base + quarter * 4 + r;
        if (m < n_nodes) {
#pragma unroll
            for (int q = 0; q < 4; ++q) {
                int j = q * 16 + c;
                float v = acc[q][r] + b1[j];
                Xpk[(size_t)m * 128 + 64 + j] = packhl(fmaxf(v, 0.f));
            }
        }
    }
}

// ---------------------------------------------------------------------------
// CSR build (int32 edge_index)
// ---------------------------------------------------------------------------
__global__ void k_hist(const int* __restrict__ ei, int* __restrict__ cnt, int E)
{
    int i = blockIdx.x * blockDim.x + threadIdx.x;
    if (i < E) atomicAdd(&cnt[ei[E + i]], 1);
}

#define SCAN_C 2048
__global__ __launch_bounds__(512) void k_scan1(const int* __restrict__ cnt,
                                               int* __restrict__ btot, int n)
{
    __shared__ int sd[512];
    int b = blockIdx.x, t = threadIdx.x;
    int base = b * SCAN_C + t * 4;
    int s = 0;
#pragma unroll
    for (int i = 0; i < 4; ++i) { int idx = base + i; if (idx < n) s += cnt[idx]; }
    sd[t] = s; __syncthreads();
    for (int off = 256; off > 0; off >>= 1) {
        if (t < off) sd[t] += sd[t + off];
        __syncthreads();
    }
    if (t == 0) btot[b] = sd[0];
}

__global__ __launch_bounds__(1024) void k_scan2(int* __restrict__ btot, int nb)
{
    __shared__ int sd[1024];
    int t = threadIdx.x;
    int v = (t < nb) ? btot[t] : 0;
    sd[t] = v; __syncthreads();
    for (int off = 1; off < 1024; off <<= 1) {
        int x = sd[t];
        int add = (t >= off) ? sd[t - off] : 0;
        __syncthreads();
        sd[t] = x + add;
        __syncthreads();
    }
    if (t < nb) btot[t] = sd[t] - v;  // exclusive
}

__global__ __launch_bounds__(512) void k_scan3(const int* __restrict__ cnt,
                                               const int* __restrict__ btot,
                                               int* __restrict__ row_ptr,
                                               int* __restrict__ cursor, int n)
{
    __shared__ int sth[512];
    int b = blockIdx.x, t = threadIdx.x;
    int base = b * SCAN_C + t * 4;
    int v[4]; int s = 0;
#pragma unroll
    for (int i = 0; i < 4; ++i) { int idx = base + i; v[i] = (idx < n) ? cnt[idx] : 0; s += v[i]; }
    sth[t] = s; __syncthreads();
    int mine = s;
    for (int off = 1; off < 512; off <<= 1) {
        int x = sth[t];
        int add = (t >= off) ? sth[t - off] : 0;
        __syncthreads();
        sth[t] = x + add;
        __syncthreads();
    }
    int carry = btot[b] + (sth[t] - mine);
#pragma unroll
    for (int i = 0; i < 4; ++i) {
        int idx = base + i;
        if (idx < n) {
            row_ptr[idx] = carry;
            cursor[idx]  = carry;
            carry += v[i];
            if (idx == n - 1) row_ptr[n] = carry;  // = E
        }
    }
}

__global__ void k_fill(const int* __restrict__ ei, int* __restrict__ cursor,
                       int* __restrict__ col_src, int E)
{
    int i = blockIdx.x * blockDim.x + threadIdx.x;
    if (i < E) {
        int dst = ei[E + i];
        int p = atomicAdd(&cursor[dst], 1);
        col_src[p] = ei[i];
    }
}

// ---------------------------------------------------------------------------
// aggregation v4: 2-node interleave (wave-uniform branches) — 8 gather loads
// in flight. One 4-B packed load per lane per edge. fp32 accumulation.
// ---------------------------------------------------------------------------
__global__ __launch_bounds__(256) void k_agg2(
    u32* Xpk, const int* __restrict__ row_ptr,
    const int* __restrict__ col_src, int n_nodes)
{
    int wid    = (blockIdx.x * blockDim.x + threadIdx.x) >> 6;
    int lane   = threadIdx.x & 63;
    int nwaves = (gridDim.x * blockDim.x) >> 6;
    for (int base = wid; base < n_nodes; base += 2 * nwaves) {
        const int nA = base;
        const int nB = base + nwaves;
        const bool hasB = nB < n_nodes;

        int eA = row_ptr[nA], endA = row_ptr[nA + 1];
        int eB = 0, endB = 0;
        if (hasB) { eB = row_ptr[nB]; endB = row_ptr[nB + 1]; }

        float accA = 0.f, accB = 0.f;
        while (true) {
            bool dA = (eA + 4 <= endA);
            bool dB = (eB + 4 <= endB);
            if (!dA && !dB) break;
            float a0 = 0.f, a1 = 0.f, a2 = 0.f, a3 = 0.f;
            float b0 = 0.f, b1 = 0.f, b2 = 0.f, b3 = 0.f;
            if (dA) {
                int s0 = col_src[eA], s1 = col_src[eA + 1];
                int s2 = col_src[eA + 2], s3 = col_src[eA + 3];
                a0 = unpackhl(Xpk[(size_t)s0 * 128 + 64 + lane]);
                a1 = unpackhl(Xpk[(size_t)s1 * 128 + 64 + lane]);
                a2 = unpackhl(Xpk[(size_t)s2 * 128 + 64 + lane]);
                a3 = unpackhl(Xpk[(size_t)s3 * 128 + 64 + lane]);
            }
            if (dB) {
                int s0 = col_src[eB], s1 = col_src[eB + 1];
                int s2 = col_src[eB + 2], s3 = col_src[eB + 3];
                b0 = unpackhl(Xpk[(size_t)s0 * 128 + 64 + lane]);
                b1 = unpackhl(Xpk[(size_t)s1 * 128 + 64 + lane]);
                b2 = unpackhl(Xpk[(size_t)s2 * 128 + 64 + lane]);
                b3 = unpackhl(Xpk[(size_t)s3 * 128 + 64 + lane]);
            }
            if (dA) { accA += (a0 + a1) + (a2 + a3); eA += 4; }
            if (dB) { accB += (b0 + b1) + (b2 + b3); eB += 4; }
        }
        for (; eA < endA; ++eA)
            accA += unpackhl(Xpk[(size_t)col_src[eA] * 128 + 64 + lane]);
        for (; eB < endB; ++eB)
            accB += unpackhl(Xpk[(size_t)col_src[eB] * 128 + 64 + lane]);

        Xpk[(size_t)nA * 128 + lane] = packhl(accA);
        if (hasB) Xpk[(size_t)nB * 128 + lane] = packhl(accB);
    }
}

// ---------------------------------------------------------------------------
// Wic[l][j][k] = sum_m w_ih[j][m] * gg_w[l][k][m]  (fp32 staging)
// ---------------------------------------------------------------------------
__global__ void k_wic(const float* __restrict__ gg_w, const float* __restrict__ w_ih,
                      float* __restrict__ Wic)
{
    int idx = blockIdx.x * blockDim.x + threadIdx.x;
    if (idx < NUM_LAYERS * 192 * 64) {
        int l = idx / (192 * 64);
        int j = (idx / 64) % 192;
        int k = idx % 64;
        const float* gw = gg_w + ((size_t)l * 64 + k) * 64;
        const float* wi = w_ih + (size_t)j * 64;
        float acc = 0.f;
#pragma unroll 4
        for (int m = 0; m < 64; ++m) acc = fmaf(wi[m], gw[m], acc);
        Wic[idx] = acc;
    }
}

// ---------------------------------------------------------------------------
// W' pack: [3][256][128] f16 hi/lo, SPLIT arrays. Rows 0-63: r; 64-127: z
// (both [Wic | whh]); 128-191: [Wic_n | 0]; 192-255: [0 | whh_n].
// ---------------------------------------------------------------------------
__global__ void k_wpack(const float* __restrict__ Wic, const float* __restrict__ whh,
                        u16* __restrict__ Wphi, u16* __restrict__ Wplo)
{
    int idx = blockIdx.x * 256 + threadIdx.x;
    if (idx >= NUM_LAYERS * 256 * 128) return;
    int l = idx / (256 * 128);
    int n = (idx / 128) & 255;
    int k = idx & 127;
    float v;
    if (n < 128)      v = (k < 64) ? Wic[((size_t)l * 192 + n) * 64 + k] : whh[(size_t)n * 64 + (k - 64)];
    else if (n < 192) v = (k < 64) ? Wic[((size_t)l * 192 + n) * 64 + k] : 0.f;
    else              v = (k < 64) ? 0.f : whh[(size_t)(n - 64) * 64 + (k - 64)];
    u16 hi = f2h(v);
    Wphi[idx] = hi;
    Wplo[idx] = f2h(v - h2f(hi));
}

// ---------------------------------------------------------------------------
// fused GRU v10 — r19-verified core + weights in LDS (r23: 175 -> ~65 us).
// block = 512 thr (8 waves x 16 nodes = 128 nodes); Wphi/Wplo staged in LDS
// [256][136] u16 (row stride 272 B -> bank = 4*row mod 32 -> conflict-free),
// one barrier, B-frags via ds_read_b128. Numerics bit-identical to r19.
// ---------------------------------------------------------------------------
#define WPAD 136
__global__ __launch_bounds__(512) void k_gru10(
    u32* Xpk,
    const u16* __restrict__ Wphi, const u16* __restrict__ Wplo,
    const float* __restrict__ b_ih, const float* __restrict__ b_hh, int n_nodes)
{
    __shared__ u16 wlh[256][WPAD];  // 69.6 KB
    __shared__ u16 wll[256][WPAD];  // 69.6 KB

    const int tid = threadIdx.x;

    // cooperative staging: 4096 uint4 per array (coalesced 16-B loads)
    {
        const uint4* gh = reinterpret_cast<const uint4*>(Wphi);
        const uint4* gl = reinterpret_cast<const uint4*>(Wplo);
#pragma unroll
        for (int i = 0; i < 8; ++i) {
            int e   = tid + i * 512;          // 0..4095
            int row = e >> 4;
            int c8  = (e & 15) * 8;           // u16 col
            *reinterpret_cast<uint4*>(&wlh[row][c8]) = gh[e];
            *reinterpret_cast<uint4*>(&wll[row][c8]) = gl[e];
        }
    }
    __syncthreads();

    const int l    = tid & 63;
    const int wv   = tid >> 6;                 // 0..7
    const int base = blockIdx.x * 128 + wv * 16;
    if (base >= n_nodes) return;

    const int lrow = l & 15;
    const int lk   = (l >> 4) * 8;

    int arow = base + lrow;
    if (arow > n_nodes - 1) arow = n_nodes - 1;
    const u32* xp = Xpk + (size_t)arow * 128;

    f32x4 acc[16];
#pragma unroll
    for (int t = 0; t < 16; ++t) acc[t] = f32x4{0.f, 0.f, 0.f, 0.f};

#pragma unroll
    for (int s = 0; s < 4; ++s) {
        const uint4* pa = reinterpret_cast<const uint4*>(xp + s * 32 + lk);
        uint4 w0 = pa[0], w1 = pa[1];
        s16x8 p0 = __builtin_bit_cast(s16x8, w0);  // hi0,lo0,hi1,lo1,...
        s16x8 p1 = __builtin_bit_cast(s16x8, w1);
        s16x8 ahi = __builtin_shufflevector(p0, p1, 0, 2, 4, 6, 8, 10, 12, 14);
        s16x8 alo = __builtin_shufflevector(p0, p1, 1, 3, 5, 7, 9, 11, 13, 15);
#pragma unroll
        for (int t = 0; t < 16; ++t) {
            const bool valid = (t < 8) || (t < 12 ? (s < 2) : (s >= 2));
            if (!valid) continue;  // compile-time after unroll
            const int wr = t * 16 + lrow;
            const int wc = s * 32 + lk;
            s16x8 bhi = *reinterpret_cast<const s16x8*>(&wlh[wr][wc]);
            s16x8 blo = *reinterpret_cast<const s16x8*>(&wll[wr][wc]);
            acc[t] = mfma_f16(ahi, bhi, acc[t]);
            acc[t] = mfma_f16(alo, bhi, acc[t]);
            acc[t] = mfma_f16(ahi, blo, acc[t]);
            acc[t] = mfma_f16(alo, blo, acc[t]);
        }
    }

    const int quarter = l >> 4;
    const int c = lrow;
#pragma unroll
    for (int r = 0; r < 4; ++r) {
        int m = base + quarter * 4 + r;
        if (m < n_nodes) {
            u32* hp = Xpk + (size_t)m * 128 + 64;
#pragma unroll
            for (int q = 0; q < 4; ++q) {
                int j = q * 16 + c;
                float rv = acc[q][r]      + b_ih[j]       + b_hh[j];
                float zv = acc[4 + q][r]  + b_ih[64 + j]  + b_hh[64 + j];
                float iv = acc[8 + q][r]  + b_ih[128 + j];
                float hv = acc[12 + q][r] + b_hh[128 + j];
                rv = 1.f / (1.f + __expf(-rv));
                zv = 1.f / (1.f + __expf(-zv));
                float x2 = iv + rv * hv;
                float nn = 1.f - 2.f / (__expf(2.f * x2) + 1.f);  // tanh, inf-safe
                float hold = unpackhl(hp[j]);
                hp[j] = packhl((1.f - zv) * nn + zv * hold);
            }
        }
    }
}

// ---------------------------------------------------------------------------
// out = softmax(h @ w2.T + b2); h read from packed Xpk h-half
// ---------------------------------------------------------------------------
__global__ __launch_bounds__(256) void k_out(
    const u32* __restrict__ Xpk, const float* __restrict__ w2,
    const float* __restrict__ b2, float* __restrict__ out, int n_nodes)
{
    const int tid = threadIdx.x, lane = tid & 63;
    float wreg[64];
    float bias = 0.f;
    if (lane < NCLASS) {
#pragma unroll
        for (int k = 0; k < 64; k += 4) {
            float4 v = *reinterpret_cast<const float4*>(&w2[lane * HID + k]);
            wreg[k] = v.x; wreg[k + 1] = v.y; wreg[k + 2] = v.z; wreg[k + 3] = v.w;
        }
        bias = b2[lane];
    } else {
#pragma unroll
        for (int k = 0; k < 64; ++k) wreg[k] = 0.f;
    }
    int wid    = (blockIdx.x * blockDim.x + tid) >> 6;
    int nwaves = (gridDim.x * blockDim.x) >> 6;
    for (int node = wid; node < n_nodes; node += nwaves) {
        const uint4* p4 = reinterpret_cast<const uint4*>(Xpk + (size_t)node * 128 + 64);
        float a0 = bias, a1 = 0.f, a2 = 0.f, a3 = 0.f;
#pragma unroll
        for (int kq = 0; kq < 16; ++kq) {
            uint4 v = p4[kq];
            a0 = fmaf(unpackhl(v.x), wreg[4 * kq + 0], a0);
            a1 = fmaf(unpackhl(v.y), wreg[4 * kq + 1], a1);
            a2 = fmaf(unpackhl(v.z), wreg[4 * kq + 2], a2);
            a3 = fmaf(unpackhl(v.w), wreg[4 * kq + 3], a3);
        }
        float lg = (lane < NCLASS) ? (a0 + a1) + (a2 + a3) : -INFINITY;
        float m = lg;
#pragma unroll
        for (int off = 32; off > 0; off >>= 1) m = fmaxf(m, __shfl_xor(m, off, 64));
        float p = (lane < NCLASS) ? __expf(lg - m) : 0.f;
        float s = p;
#pragma unroll
        for (int off = 32; off > 0; off >>= 1) s += __shfl_xor(s, off, 64);
        if (lane < NCLASS) out[(size_t)node * NCLASS + lane] = p / s;
    }
}

// ---------------------------------------------------------------------------
extern "C" void kernel_launch(void* const* d_in, const int* in_sizes, int n_in,
                              void* d_out, int out_size, void* d_ws, size_t ws_size,
                              hipStream_t stream)
{
    const float* x    = (const float*)d_in[0];
    const int*   ei   = (const int*)d_in[1];    // int32 per harness contract
    const float* w1   = (const float*)d_in[2];
    const float* b1   = (const float*)d_in[3];
    const float* gg_w = (const float*)d_in[4];
    const float* w_ih = (const float*)d_in[5];
    const float* w_hh = (const float*)d_in[6];
    const float* b_ih = (const float*)d_in[7];
    const float* b_hh = (const float*)d_in[8];
    const float* w2   = (const float*)d_in[9];
    const float* b2   = (const float*)d_in[10];
    float*       out  = (float*)d_out;

    const int n = in_sizes[0] / NFEAT;   // 200000
    const int E = in_sizes[1] / 2;       // 1200000

    // workspace carve (~110 MB, proven envelope), 256-B aligned slots
    char* ws0 = (char*)d_ws;
    char* ws  = ws0;
    auto carve = [&](size_t bytes) {
        char* p = ws;
        ws += (bytes + 255) & ~(size_t)255;
        return p;
    };
    u32*   Xpk     = (u32*)carve((size_t)n * 128 * 4);               // 102.4 MB
    float* Wic     = (float*)carve((size_t)NUM_LAYERS * 192 * 64 * 4);
    u16*   Wphi    = (u16*)carve((size_t)NUM_LAYERS * 256 * 128 * 2);
    u16*   Wplo    = (u16*)carve((size_t)NUM_LAYERS * 256 * 128 * 2);
    u16*   W1h     = (u16*)carve((size_t)64 * 256 * 2);
    u16*   W1l     = (u16*)carve((size_t)64 * 256 * 2);
    int*   row_ptr = (int*)carve((size_t)(n + 1) * 4);
    int*   col_src = (int*)carve((size_t)E * 4);
    int*   cnt     = (int*)carve((size_t)n * 4);
    int*   cursor  = (int*)carve((size_t)n * 4);
    int*   btot    = (int*)carve(8192);

    const int nb = (n + SCAN_C - 1) / SCAN_C;

    hipMemsetAsync(cnt, 0, (size_t)n * 4, stream);
    k_wic<<<(NUM_LAYERS * 192 * 64 + 255) / 256, 256, 0, stream>>>(gg_w, w_ih, Wic);
    k_wpack<<<(NUM_LAYERS * 256 * 128 + 255) / 256, 256, 0, stream>>>(Wic, w_hh, Wphi, Wplo);
    k_w1pack<<<(64 * 256 + 255) / 256, 256, 0, stream>>>(w1, W1h, W1l);
    k_lin2<<<(n + 127) / 128, 512, 0, stream>>>(x, W1h, W1l, b1, Xpk, n);
    k_hist<<<(E + 255) / 256, 256, 0, stream>>>(ei, cnt, E);
    k_scan1<<<nb, 512, 0, stream>>>(cnt, btot, n);
    k_scan2<<<1, 1024, 0, stream>>>(btot, nb);
    k_scan3<<<nb, 512, 0, stream>>>(cnt, btot, row_ptr, cursor, n);
    k_fill<<<(E + 255) / 256, 256, 0, stream>>>(ei, cursor, col_src, E);

    const int gblocks = (n + 127) / 128;  // 1563
    for (int l = 0; l < NUM_LAYERS; ++l) {
        k_agg2<<<2048, 256, 0, stream>>>(Xpk, row_ptr, col_src, n);
        k_gru10<<<gblocks, 512, 0, stream>>>(Xpk,
                                             Wphi + (size_t)l * 256 * 128,
                                             Wplo + (size_t)l * 256 * 128,
                                             b_ih, b_hh, n);
    }
    k_out<<<2048, 256, 0, stream>>>(Xpk, w2, b2, out, n);
}

// Round 25
// 696.512 us; speedup vs baseline: 1.8747x; 1.1331x over previous
//
#include <hip/hip_runtime.h>
#include <hip/hip_bf16.h>

#define NFEAT 256
#define HID 64
#define NCLASS 40
#define NUM_LAYERS 3

typedef unsigned short u16;
typedef unsigned int   u32;
typedef float    f32x4 __attribute__((ext_vector_type(4)));
typedef short    s16x8 __attribute__((ext_vector_type(8)));
typedef _Float16 h16x8 __attribute__((ext_vector_type(8)));

// fp16 hi/lo split: hi = (f16)f, lo = (f16)(f - hi) -> ~22-23 mantissa bits
__device__ __forceinline__ u16 f2h(float f) {
    _Float16 h = (_Float16)f;
    return __builtin_bit_cast(u16, h);
}
__device__ __forceinline__ float h2f(u16 s) {
    return (float)__builtin_bit_cast(_Float16, s);
}
__device__ __forceinline__ u32 packhl(float f) {
    u16 hi = f2h(f);
    u16 lo = f2h(f - h2f(hi));
    return (u32)hi | ((u32)lo << 16);
}
__device__ __forceinline__ float unpackhl(u32 v) {
    return h2f((u16)v) + h2f((u16)(v >> 16));
}

// BUILTIN MFMA (r18/r19 lesson: raw inline-asm MFMA is opaque to the hazard
// recognizer; the builtin gets compiler-inserted wait states. r19-verified.)
__device__ __forceinline__ f32x4 mfma_f16(s16x8 a, s16x8 b, f32x4 c) {
    return __builtin_amdgcn_mfma_f32_16x16x32_f16(
        __builtin_bit_cast(h16x8, a), __builtin_bit_cast(h16x8, b), c, 0, 0, 0);
}

// ---------------------------------------------------------------------------
// w1 pack: [64][256] fp32 -> f16 hi/lo split arrays
// ---------------------------------------------------------------------------
__global__ void k_w1pack(const float* __restrict__ w1,
                         u16* __restrict__ W1h, u16* __restrict__ W1l)
{
    int idx = blockIdx.x * 256 + threadIdx.x;
    if (idx >= 64 * 256) return;
    float v = w1[idx];
    u16 hi = f2h(v);
    W1h[idx] = hi;
    W1l[idx] = f2h(v - h2f(hi));
}

// ---------------------------------------------------------------------------
// w2 pack: [48][64] f16 hi/lo (rows 40-47 zero-padded)
// ---------------------------------------------------------------------------
__global__ void k_w2pack(const float* __restrict__ w2,
                         u16* __restrict__ W2h, u16* __restrict__ W2l)
{
    int idx = blockIdx.x * 256 + threadIdx.x;
    if (idx >= 48 * 64) return;
    int r = idx >> 6;
    float v = (r < NCLASS) ? w2[idx] : 0.f;
    u16 hi = f2h(v);
    W2h[idx] = hi;
    W2l[idx] = f2h(v - h2f(hi));
}

// ---------------------------------------------------------------------------
// lin1 v2 (MFMA, r24-verified): h = relu(x @ w1.T + b1) -> Xpk[:,64:128]
// ---------------------------------------------------------------------------
#define W1PAD 264
__global__ __launch_bounds__(512) void k_lin2(
    const float* __restrict__ x,
    const u16* __restrict__ W1h, const u16* __restrict__ W1l,
    const float* __restrict__ b1, u32* Xpk, int n_nodes)
{
    __shared__ u16 w1h[64][W1PAD];  // 33.8 KB
    __shared__ u16 w1l[64][W1PAD];  // 33.8 KB

    const int tid = threadIdx.x;
    {
        const uint4* gh = reinterpret_cast<const uint4*>(W1h);
        const uint4* gl = reinterpret_cast<const uint4*>(W1l);
#pragma unroll
        for (int i = 0; i < 4; ++i) {
            int e   = tid + i * 512;   // 0..2047
            int row = e >> 5;
            int c8  = (e & 31) * 8;
            *reinterpret_cast<uint4*>(&w1h[row][c8]) = gh[e];
            *reinterpret_cast<uint4*>(&w1l[row][c8]) = gl[e];
        }
    }
    __syncthreads();

    const int l    = tid & 63;
    const int wv   = tid >> 6;
    const int base = blockIdx.x * 128 + wv * 16;
    if (base >= n_nodes) return;

    const int lrow = l & 15;
    const int lk   = (l >> 4) * 8;

    int arow = base + lrow;
    if (arow > n_nodes - 1) arow = n_nodes - 1;
    const float* xr = x + (size_t)arow * NFEAT;

    f32x4 acc[4];
#pragma unroll
    for (int t = 0; t < 4; ++t) acc[t] = f32x4{0.f, 0.f, 0.f, 0.f};

#pragma unroll
    for (int s = 0; s < 8; ++s) {
        const float4* pa = reinterpret_cast<const float4*>(xr + s * 32 + lk);
        float4 f0 = pa[0], f1 = pa[1];
        const float fv[8] = {f0.x, f0.y, f0.z, f0.w, f1.x, f1.y, f1.z, f1.w};
        s16x8 ahi, alo;
#pragma unroll
        for (int i2 = 0; i2 < 8; ++i2) {
            u16 hi = f2h(fv[i2]);
            u16 lo = f2h(fv[i2] - h2f(hi));
            ahi[i2] = (short)hi;
            alo[i2] = (short)lo;
        }
#pragma unroll
        for (int t = 0; t < 4; ++t) {
            s16x8 bhi = *reinterpret_cast<const s16x8*>(&w1h[t * 16 + lrow][s * 32 + lk]);
            s16x8 blo = *reinterpret_cast<const s16x8*>(&w1l[t * 16 + lrow][s * 32 + lk]);
            acc[t] = mfma_f16(ahi, bhi, acc[t]);
            acc[t] = mfma_f16(alo, bhi, acc[t]);
            acc[t] = mfma_f16(ahi, blo, acc[t]);
            acc[t] = mfma_f16(alo, blo, acc[t]);
        }
    }

    const int quarter = l >> 4;
    const int c = lrow;
#pragma unroll
    for (int r = 0; r < 4; ++r) {
        int m = base + quarter * 4 + r;
        if (m < n_nodes) {
#pragma unroll
            for (int q = 0; q < 4; ++q) {
                int j = q * 16 + c;
                float v = acc[q][r] + b1[j];
                Xpk[(size_t)m * 128 + 64 + j] = packhl(fmaxf(v, 0.f));
            }
        }
    }
}

// ---------------------------------------------------------------------------
// CSR build (int32 edge_index)
// ---------------------------------------------------------------------------
__global__ void k_hist(const int* __restrict__ ei, int* __restrict__ cnt, int E)
{
    int i = blockIdx.x * blockDim.x + threadIdx.x;
    if (i < E) atomicAdd(&cnt[ei[E + i]], 1);
}

#define SCAN_C 2048
__global__ __launch_bounds__(512) void k_scan1(const int* __restrict__ cnt,
                                               int* __restrict__ btot, int n)
{
    __shared__ int sd[512];
    int b = blockIdx.x, t = threadIdx.x;
    int base = b * SCAN_C + t * 4;
    int s = 0;
#pragma unroll
    for (int i = 0; i < 4; ++i) { int idx = base + i; if (idx < n) s += cnt[idx]; }
    sd[t] = s; __syncthreads();
    for (int off = 256; off > 0; off >>= 1) {
        if (t < off) sd[t] += sd[t + off];
        __syncthreads();
    }
    if (t == 0) btot[b] = sd[0];
}

__global__ __launch_bounds__(1024) void k_scan2(int* __restrict__ btot, int nb)
{
    __shared__ int sd[1024];
    int t = threadIdx.x;
    int v = (t < nb) ? btot[t] : 0;
    sd[t] = v; __syncthreads();
    for (int off = 1; off < 1024; off <<= 1) {
        int x = sd[t];
        int add = (t >= off) ? sd[t - off] : 0;
        __syncthreads();
        sd[t] = x + add;
        __syncthreads();
    }
    if (t < nb) btot[t] = sd[t] - v;  // exclusive
}

__global__ __launch_bounds__(512) void k_scan3(const int* __restrict__ cnt,
                                               const int* __restrict__ btot,
                                               int* __restrict__ row_ptr,
                                               int* __restrict__ cursor, int n)
{
    __shared__ int sth[512];
    int b = blockIdx.x, t = threadIdx.x;
    int base = b * SCAN_C + t * 4;
    int v[4]; int s = 0;
#pragma unroll
    for (int i = 0; i < 4; ++i) { int idx = base + i; v[i] = (idx < n) ? cnt[idx] : 0; s += v[i]; }
    sth[t] = s; __syncthreads();
    int mine = s;
    for (int off = 1; off < 512; off <<= 1) {
        int x = sth[t];
        int add = (t >= off) ? sth[t - off] : 0;
        __syncthreads();
        sth[t] = x + add;
        __syncthreads();
    }
    int carry = btot[b] + (sth[t] - mine);
#pragma unroll
    for (int i = 0; i < 4; ++i) {
        int idx = base + i;
        if (idx < n) {
            row_ptr[idx] = carry;
            cursor[idx]  = carry;
            carry += v[i];
            if (idx == n - 1) row_ptr[n] = carry;  // = E
        }
    }
}

__global__ void k_fill(const int* __restrict__ ei, int* __restrict__ cursor,
                       int* __restrict__ col_src, int E)
{
    int i = blockIdx.x * blockDim.x + threadIdx.x;
    if (i < E) {
        int dst = ei[E + i];
        int p = atomicAdd(&cursor[dst], 1);
        col_src[p] = ei[i];
    }
}

// ---------------------------------------------------------------------------
// aggregation v4: 2-node interleave (wave-uniform branches) — 8 gather loads
// in flight. One 4-B packed load per lane per edge. fp32 accumulation.
// ---------------------------------------------------------------------------
__global__ __launch_bounds__(256) void k_agg2(
    u32* Xpk, const int* __restrict__ row_ptr,
    const int* __restrict__ col_src, int n_nodes)
{
    int wid    = (blockIdx.x * blockDim.x + threadIdx.x) >> 6;
    int lane   = threadIdx.x & 63;
    int nwaves = (gridDim.x * blockDim.x) >> 6;
    for (int base = wid; base < n_nodes; base += 2 * nwaves) {
        const int nA = base;
        const int nB = base + nwaves;
        const bool hasB = nB < n_nodes;

        int eA = row_ptr[nA], endA = row_ptr[nA + 1];
        int eB = 0, endB = 0;
        if (hasB) { eB = row_ptr[nB]; endB = row_ptr[nB + 1]; }

        float accA = 0.f, accB = 0.f;
        while (true) {
            bool dA = (eA + 4 <= endA);
            bool dB = (eB + 4 <= endB);
            if (!dA && !dB) break;
            float a0 = 0.f, a1 = 0.f, a2 = 0.f, a3 = 0.f;
            float b0 = 0.f, b1 = 0.f, b2 = 0.f, b3 = 0.f;
            if (dA) {
                int s0 = col_src[eA], s1 = col_src[eA + 1];
                int s2 = col_src[eA + 2], s3 = col_src[eA + 3];
                a0 = unpackhl(Xpk[(size_t)s0 * 128 + 64 + lane]);
                a1 = unpackhl(Xpk[(size_t)s1 * 128 + 64 + lane]);
                a2 = unpackhl(Xpk[(size_t)s2 * 128 + 64 + lane]);
                a3 = unpackhl(Xpk[(size_t)s3 * 128 + 64 + lane]);
            }
            if (dB) {
                int s0 = col_src[eB], s1 = col_src[eB + 1];
                int s2 = col_src[eB + 2], s3 = col_src[eB + 3];
                b0 = unpackhl(Xpk[(size_t)s0 * 128 + 64 + lane]);
                b1 = unpackhl(Xpk[(size_t)s1 * 128 + 64 + lane]);
                b2 = unpackhl(Xpk[(size_t)s2 * 128 + 64 + lane]);
                b3 = unpackhl(Xpk[(size_t)s3 * 128 + 64 + lane]);
            }
            if (dA) { accA += (a0 + a1) + (a2 + a3); eA += 4; }
            if (dB) { accB += (b0 + b1) + (b2 + b3); eB += 4; }
        }
        for (; eA < endA; ++eA)
            accA += unpackhl(Xpk[(size_t)col_src[eA] * 128 + 64 + lane]);
        for (; eB < endB; ++eB)
            accB += unpackhl(Xpk[(size_t)col_src[eB] * 128 + 64 + lane]);

        Xpk[(size_t)nA * 128 + lane] = packhl(accA);
        if (hasB) Xpk[(size_t)nB * 128 + lane] = packhl(accB);
    }
}

// ---------------------------------------------------------------------------
// Wic[l][j][k] = sum_m w_ih[j][m] * gg_w[l][k][m]  (fp32 staging)
// ---------------------------------------------------------------------------
__global__ void k_wic(const float* __restrict__ gg_w, const float* __restrict__ w_ih,
                      float* __restrict__ Wic)
{
    int idx = blockIdx.x * blockDim.x + threadIdx.x;
    if (idx < NUM_LAYERS * 192 * 64) {
        int l = idx / (192 * 64);
        int j = (idx / 64) % 192;
        int k = idx % 64;
        const float* gw = gg_w + ((size_t)l * 64 + k) * 64;
        const float* wi = w_ih + (size_t)j * 64;
        float acc = 0.f;
#pragma unroll 4
        for (int m = 0; m < 64; ++m) acc = fmaf(wi[m], gw[m], acc);
        Wic[idx] = acc;
    }
}

// ---------------------------------------------------------------------------
// W' pack: [3][256][128] f16 hi/lo, SPLIT arrays. Rows 0-63: r; 64-127: z
// (both [Wic | whh]); 128-191: [Wic_n | 0]; 192-255: [0 | whh_n].
// ---------------------------------------------------------------------------
__global__ void k_wpack(const float* __restrict__ Wic, const float* __restrict__ whh,
                        u16* __restrict__ Wphi, u16* __restrict__ Wplo)
{
    int idx = blockIdx.x * 256 + threadIdx.x;
    if (idx >= NUM_LAYERS * 256 * 128) return;
    int l = idx / (256 * 128);
    int n = (idx / 128) & 255;
    int k = idx & 127;
    float v;
    if (n < 128)      v = (k < 64) ? Wic[((size_t)l * 192 + n) * 64 + k] : whh[(size_t)n * 64 + (k - 64)];
    else if (n < 192) v = (k < 64) ? Wic[((size_t)l * 192 + n) * 64 + k] : 0.f;
    else              v = (k < 64) ? 0.f : whh[(size_t)(n - 64) * 64 + (k - 64)];
    u16 hi = f2h(v);
    Wphi[idx] = hi;
    Wplo[idx] = f2h(v - h2f(hi));
}

// ---------------------------------------------------------------------------
// fused GRU v10 — r19-verified core + weights in LDS (r23: 175 -> ~65 us).
// ---------------------------------------------------------------------------
#define WPAD 136
__global__ __launch_bounds__(512) void k_gru10(
    u32* Xpk,
    const u16* __restrict__ Wphi, const u16* __restrict__ Wplo,
    const float* __restrict__ b_ih, const float* __restrict__ b_hh, int n_nodes)
{
    __shared__ u16 wlh[256][WPAD];  // 69.6 KB
    __shared__ u16 wll[256][WPAD];  // 69.6 KB

    const int tid = threadIdx.x;
    {
        const uint4* gh = reinterpret_cast<const uint4*>(Wphi);
        const uint4* gl = reinterpret_cast<const uint4*>(Wplo);
#pragma unroll
        for (int i = 0; i < 8; ++i) {
            int e   = tid + i * 512;          // 0..4095
            int row = e >> 4;
            int c8  = (e & 15) * 8;           // u16 col
            *reinterpret_cast<uint4*>(&wlh[row][c8]) = gh[e];
            *reinterpret_cast<uint4*>(&wll[row][c8]) = gl[e];
        }
    }
    __syncthreads();

    const int l    = tid & 63;
    const int wv   = tid >> 6;                 // 0..7
    const int base = blockIdx.x * 128 + wv * 16;
    if (base >= n_nodes) return;

    const int lrow = l & 15;
    const int lk   = (l >> 4) * 8;

    int arow = base + lrow;
    if (arow > n_nodes - 1) arow = n_nodes - 1;
    const u32* xp = Xpk + (size_t)arow * 128;

    f32x4 acc[16];
#pragma unroll
    for (int t = 0; t < 16; ++t) acc[t] = f32x4{0.f, 0.f, 0.f, 0.f};

#pragma unroll
    for (int s = 0; s < 4; ++s) {
        const uint4* pa = reinterpret_cast<const uint4*>(xp + s * 32 + lk);
        uint4 w0 = pa[0], w1 = pa[1];
        s16x8 p0 = __builtin_bit_cast(s16x8, w0);  // hi0,lo0,hi1,lo1,...
        s16x8 p1 = __builtin_bit_cast(s16x8, w1);
        s16x8 ahi = __builtin_shufflevector(p0, p1, 0, 2, 4, 6, 8, 10, 12, 14);
        s16x8 alo = __builtin_shufflevector(p0, p1, 1, 3, 5, 7, 9, 11, 13, 15);
#pragma unroll
        for (int t = 0; t < 16; ++t) {
            const bool valid = (t < 8) || (t < 12 ? (s < 2) : (s >= 2));
            if (!valid) continue;  // compile-time after unroll
            const int wr = t * 16 + lrow;
            const int wc = s * 32 + lk;
            s16x8 bhi = *reinterpret_cast<const s16x8*>(&wlh[wr][wc]);
            s16x8 blo = *reinterpret_cast<const s16x8*>(&wll[wr][wc]);
            acc[t] = mfma_f16(ahi, bhi, acc[t]);
            acc[t] = mfma_f16(alo, bhi, acc[t]);
            acc[t] = mfma_f16(ahi, blo, acc[t]);
            acc[t] = mfma_f16(alo, blo, acc[t]);
        }
    }

    const int quarter = l >> 4;
    const int c = lrow;
#pragma unroll
    for (int r = 0; r < 4; ++r) {
        int m = base + quarter * 4 + r;
        if (m < n_nodes) {
            u32* hp = Xpk + (size_t)m * 128 + 64;
#pragma unroll
            for (int q = 0; q < 4; ++q) {
                int j = q * 16 + c;
                float rv = acc[q][r]      + b_ih[j]       + b_hh[j];
                float zv = acc[4 + q][r]  + b_ih[64 + j]  + b_hh[64 + j];
                float iv = acc[8 + q][r]  + b_ih[128 + j];
                float hv = acc[12 + q][r] + b_hh[128 + j];
                rv = 1.f / (1.f + __expf(-rv));
                zv = 1.f / (1.f + __expf(-zv));
                float x2 = iv + rv * hv;
                float nn = 1.f - 2.f / (__expf(2.f * x2) + 1.f);  // tanh, inf-safe
                float hold = unpackhl(hp[j]);
                hp[j] = packhl((1.f - zv) * nn + zv * hold);
            }
        }
    }
}

// ---------------------------------------------------------------------------
// out v2 (MFMA): softmax(h @ w2.T + b2). r24 evidence: VALU k_out at 143 us,
// VALUBusy 70%, MfmaUtil 0 — matmul-shaped on the wrong pipe (lin1 disease).
// 3 class-tiles (48 cols, pad biased -1e30 -> exp 0), 2 k-steps, 4-term
// hi/lo MFMA (24/wave). Softmax per node: the 40 logits live in 3 acc regs
// across the node's 16-lane quarter -> shfl_xor {1,2,4,8} stays in-quarter
// (lane bits 0-3), giving in-register max/sum. Scattered dword stores j<40.
// ---------------------------------------------------------------------------
__global__ __launch_bounds__(256) void k_out2(
    const u32* __restrict__ Xpk,
    const u16* __restrict__ W2h, const u16* __restrict__ W2l,
    const float* __restrict__ b2, float* __restrict__ out, int n_nodes)
{
    const int l    = threadIdx.x & 63;
    const int wv   = threadIdx.x >> 6;
    const int base = blockIdx.x * 64 + wv * 16;
    if (base >= n_nodes) return;

    const int lrow = l & 15;
    const int lk   = (l >> 4) * 8;

    int arow = base + lrow;
    if (arow > n_nodes - 1) arow = n_nodes - 1;
    const u32* xp = Xpk + (size_t)arow * 128 + 64;   // h half

    f32x4 acc[3];
#pragma unroll
    for (int t = 0; t < 3; ++t) acc[t] = f32x4{0.f, 0.f, 0.f, 0.f};

#pragma unroll
    for (int s = 0; s < 2; ++s) {
        const uint4* pa = reinterpret_cast<const uint4*>(xp + s * 32 + lk);
        uint4 w0 = pa[0], w1 = pa[1];
        s16x8 p0 = __builtin_bit_cast(s16x8, w0);
        s16x8 p1 = __builtin_bit_cast(s16x8, w1);
        s16x8 ahi = __builtin_shufflevector(p0, p1, 0, 2, 4, 6, 8, 10, 12, 14);
        s16x8 alo = __builtin_shufflevector(p0, p1, 1, 3, 5, 7, 9, 11, 13, 15);
#pragma unroll
        for (int t = 0; t < 3; ++t) {
            const size_t woff = (size_t)(t * 16 + lrow) * 64 + s * 32 + lk;
            s16x8 bhi = *reinterpret_cast<const s16x8*>(W2h + woff);
            s16x8 blo = *reinterpret_cast<const s16x8*>(W2l + woff);
            acc[t] = mfma_f16(ahi, bhi, acc[t]);
            acc[t] = mfma_f16(alo, bhi, acc[t]);
            acc[t] = mfma_f16(ahi, blo, acc[t]);
            acc[t] = mfma_f16(alo, blo, acc[t]);
        }
    }

    const int quarter = l >> 4;
    const int c = lrow;
    // per-lane biases for its 3 classes (pad classes get -1e30 -> exp 0)
    float bv[3];
#pragma unroll
    for (int t = 0; t < 3; ++t) {
        int j = t * 16 + c;
        bv[t] = (j < NCLASS) ? b2[j] : -1e30f;
    }

#pragma unroll
    for (int r = 0; r < 4; ++r) {
        int m = base + quarter * 4 + r;
        float lg0 = acc[0][r] + bv[0];
        float lg1 = acc[1][r] + bv[1];
        float lg2 = acc[2][r] + bv[2];
        float mx = fmaxf(lg0, fmaxf(lg1, lg2));
#pragma unroll
        for (int off = 1; off < 16; off <<= 1)
            mx = fmaxf(mx, __shfl_xor(mx, off, 64));
        float e0 = __expf(lg0 - mx);
        float e1 = __expf(lg1 - mx);
        float e2 = __expf(lg2 - mx);
        float sm = e0 + e1 + e2;
#pragma unroll
        for (int off = 1; off < 16; off <<= 1)
            sm += __shfl_xor(sm, off, 64);
        float inv = 1.f / sm;
        if (m < n_nodes) {
            float ev[3] = {e0, e1, e2};
#pragma unroll
            for (int t = 0; t < 3; ++t) {
                int j = t * 16 + c;
                if (j < NCLASS) out[(size_t)m * NCLASS + j] = ev[t] * inv;
            }
        }
    }
}

// ---------------------------------------------------------------------------
extern "C" void kernel_launch(void* const* d_in, const int* in_sizes, int n_in,
                              void* d_out, int out_size, void* d_ws, size_t ws_size,
                              hipStream_t stream)
{
    const float* x    = (const float*)d_in[0];
    const int*   ei   = (const int*)d_in[1];    // int32 per harness contract
    const float* w1   = (const float*)d_in[2];
    const float* b1   = (const float*)d_in[3];
    const float* gg_w = (const float*)d_in[4];
    const float* w_ih = (const float*)d_in[5];
    const float* w_hh = (const float*)d_in[6];
    const float* b_ih = (const float*)d_in[7];
    const float* b_hh = (const float*)d_in[8];
    const float* w2   = (const float*)d_in[9];
    const float* b2   = (const float*)d_in[10];
    float*       out  = (float*)d_out;

    const int n = in_sizes[0] / NFEAT;   // 200000
    const int E = in_sizes[1] / 2;       // 1200000

    // workspace carve (~110 MB, proven envelope), 256-B aligned slots
    char* ws0 = (char*)d_ws;
    char* ws  = ws0;
    auto carve = [&](size_t bytes) {
        char* p = ws;
        ws += (bytes + 255) & ~(size_t)255;
        return p;
    };
    u32*   Xpk     = (u32*)carve((size_t)n * 128 * 4);               // 102.4 MB
    float* Wic     = (float*)carve((size_t)NUM_LAYERS * 192 * 64 * 4);
    u16*   Wphi    = (u16*)carve((size_t)NUM_LAYERS * 256 * 128 * 2);
    u16*   Wplo    = (u16*)carve((size_t)NUM_LAYERS * 256 * 128 * 2);
    u16*   W1h     = (u16*)carve((size_t)64 * 256 * 2);
    u16*   W1l     = (u16*)carve((size_t)64 * 256 * 2);
    u16*   W2h     = (u16*)carve((size_t)48 * 64 * 2);
    u16*   W2l     = (u16*)carve((size_t)48 * 64 * 2);
    int*   row_ptr = (int*)carve((size_t)(n + 1) * 4);
    int*   col_src = (int*)carve((size_t)E * 4);
    int*   cnt     = (int*)carve((size_t)n * 4);
    int*   cursor  = (int*)carve((size_t)n * 4);
    int*   btot    = (int*)carve(8192);

    const int nb = (n + SCAN_C - 1) / SCAN_C;

    hipMemsetAsync(cnt, 0, (size_t)n * 4, stream);
    k_wic<<<(NUM_LAYERS * 192 * 64 + 255) / 256, 256, 0, stream>>>(gg_w, w_ih, Wic);
    k_wpack<<<(NUM_LAYERS * 256 * 128 + 255) / 256, 256, 0, stream>>>(Wic, w_hh, Wphi, Wplo);
    k_w1pack<<<(64 * 256 + 255) / 256, 256, 0, stream>>>(w1, W1h, W1l);
    k_w2pack<<<(48 * 64 + 255) / 256, 256, 0, stream>>>(w2, W2h, W2l);
    k_lin2<<<(n + 127) / 128, 512, 0, stream>>>(x, W1h, W1l, b1, Xpk, n);
    k_hist<<<(E + 255) / 256, 256, 0, stream>>>(ei, cnt, E);
    k_scan1<<<nb, 512, 0, stream>>>(cnt, btot, n);
    k_scan2<<<1, 1024, 0, stream>>>(btot, nb);
    k_scan3<<<nb, 512, 0, stream>>>(cnt, btot, row_ptr, cursor, n);
    k_fill<<<(E + 255) / 256, 256, 0, stream>>>(ei, cursor, col_src, E);

    const int gblocks = (n + 127) / 128;  // 1563
    for (int l = 0; l < NUM_LAYERS; ++l) {
        k_agg2<<<2048, 256, 0, stream>>>(Xpk, row_ptr, col_src, n);
        k_gru10<<<gblocks, 512, 0, stream>>>(Xpk,
                                             Wphi + (size_t)l * 256 * 128,
                                             Wplo + (size_t)l * 256 * 128,
                                             b_ih, b_hh, n);
    }
    k_out2<<<(n + 63) / 64, 256, 0, stream>>>(Xpk, W2h, W2l, b2, out, n);
}